// Round 9
// baseline (406.560 us; speedup 1.0000x reference)
//
#include <hip/hip_runtime.h>
#include <cstdint>
#include <cstddef>
#include <math.h>

typedef unsigned short u16;
typedef short bf16x8 __attribute__((ext_vector_type(8)));
typedef float f32x4 __attribute__((ext_vector_type(4)));

// ---------- helpers ----------
__device__ __forceinline__ u16 f2bf(float f) {
  union { float f; uint32_t u; } c; c.f = f;
  uint32_t u = c.u;
  return (u16)((u + 0x7FFFu + ((u >> 16) & 1u)) >> 16);
}
__device__ __forceinline__ float bf2f(u16 h) {
  union { uint32_t u; float f; } c; c.u = ((uint32_t)h) << 16;
  return c.f;
}
__device__ __forceinline__ float sigmoidf_(float x) { return 1.f / (1.f + expf(-x)); }

__device__ __forceinline__ void glds16(const void* g, void* l) {
  __builtin_amdgcn_global_load_lds((const __attribute__((address_space(1))) void*)g,
                                   (__attribute__((address_space(3))) void*)l, 16, 0, 0);
}

// column permutation: valid (s<=e) pairs compacted in natural order, invalid at end
__device__ __forceinline__ int col_rank(int p) {
  int s = p / 100, e = p - s * 100;
  int tri = (s * (s - 1)) >> 1;
  return (e >= s) ? (p - tri - s) : (5050 + tri + e);
}

// ---------- fused conv1+conv2 (fp32 exact, LDS-resident intermediate) ----------
// grid (4 t-quarters, 16 (b,g)); block (b,g,q) computes base[b][64g..64g+64)[t0..t0+25)
__global__ void front12(const float* __restrict__ in, const float* __restrict__ w1,
                        const float* __restrict__ b1, const float* __restrict__ w2,
                        const float* __restrict__ b2, float* __restrict__ base) {
  int q = blockIdx.x;
  int bg = blockIdx.y;
  int b = bg >> 2, g = bg & 3;
  int t0 = q * 25;
  __shared__ float L[64][28];
  int tid = threadIdx.x;
  for (int u = tid; u < 64 * 27; u += 256) {
    int ch = u / 27, tt = u - ch * 27;
    int t = t0 - 1 + tt;
    float s = 0.f;
    if (t >= 0 && t < 100) {
      int oc = 64 * g + ch;
      const float* wp = w1 + (size_t)oc * 300;
      const float* ip = in + ((size_t)b * 400 + 100 * g) * 100;
      s = b1[oc];
      for (int ic = 0; ic < 100; ++ic) {
        const float* r = ip + (size_t)ic * 100;
        float x0 = (t > 0) ? r[t - 1] : 0.f;
        float x1 = r[t];
        float x2 = (t < 99) ? r[t + 1] : 0.f;
        s += wp[ic * 3] * x0 + wp[ic * 3 + 1] * x1 + wp[ic * 3 + 2] * x2;
      }
      s = fmaxf(s, 0.f);
    }
    L[ch][tt] = s;
  }
  __syncthreads();
  for (int u = tid; u < 64 * 25; u += 256) {
    int ch = u / 25, tt = u - ch * 25;
    int t = t0 + tt;
    int oc = 64 * g + ch;
    const float* wp = w2 + (size_t)oc * 192;
    float s = b2[oc];
    for (int ic = 0; ic < 64; ++ic) {
      s += wp[ic * 3] * L[ic][tt] + wp[ic * 3 + 1] * L[ic][tt + 1] +
           wp[ic * 3 + 2] * L[ic][tt + 2];
    }
    base[((size_t)b * 256 + oc) * 100 + t] = fmaxf(s, 0.f);
  }
}

// fused s1/e1/p branches (all read `base`), ILP version
__global__ void conv1d_branch_v(const float* __restrict__ in, const float* __restrict__ wS,
                                const float* __restrict__ bS, const float* __restrict__ wE,
                                const float* __restrict__ bE, const float* __restrict__ wP,
                                const float* __restrict__ bP, float* __restrict__ outS,
                                float* __restrict__ outE, u16* __restrict__ Pt) {
  int idx = blockIdx.x * 256 + threadIdx.x;
  int sub = idx % 25;
  int tmp = idx / 25;
  int ocx = tmp % 640;
  int bb = tmp / 640;
  if (bb >= 4) return;
  int t4 = sub * 4;
  const float* w;
  const float* bias;
  const float* ip;
  int Cin_g, oc;
  if (ocx < 512) {
    int sel = ocx >> 8;
    oc = ocx & 255;
    w = sel ? wE : wS;
    bias = sel ? bE : bS;
    int g = oc >> 6;
    ip = in + ((size_t)bb * 256 + (size_t)g * 64) * 100 + t4;
    Cin_g = 64;
  } else {
    oc = ocx - 512;
    w = wP;
    bias = bP;
    ip = in + (size_t)bb * 256 * 100 + t4;
    Cin_g = 256;
  }
  const float* wp = w + (size_t)oc * Cin_g * 3;
  float bs = bias[oc];
  float s0 = bs, s1 = bs, s2 = bs, s3 = bs;
  #pragma unroll 4
  for (int ic = 0; ic < Cin_g; ++ic) {
    const float* r = ip + (size_t)ic * 100;
    float4 a = *(const float4*)r;
    float xm = (t4 > 0) ? r[-1] : 0.f;
    float xp = (t4 < 96) ? r[4] : 0.f;
    float w0 = wp[ic * 3 + 0], w1 = wp[ic * 3 + 1], w2 = wp[ic * 3 + 2];
    s0 += w0 * xm + w1 * a.x + w2 * a.y;
    s1 += w0 * a.x + w1 * a.y + w2 * a.z;
    s2 += w0 * a.y + w1 * a.z + w2 * a.w;
    s3 += w0 * a.z + w1 * a.w + w2 * xp;
  }
  if (ocx < 512) {
    float* out = (ocx < 256) ? outS : outE;
    float4 o;
    o.x = fmaxf(s0, 0.f); o.y = fmaxf(s1, 0.f);
    o.z = fmaxf(s2, 0.f); o.w = fmaxf(s3, 0.f);
    *(float4*)(out + ((size_t)bb * 256 + oc) * 100 + t4) = o;
  } else {
    Pt[((size_t)bb * 100 + t4 + 0) * 128 + oc] = f2bf(fmaxf(s0, 0.f));
    Pt[((size_t)bb * 100 + t4 + 1) * 128 + oc] = f2bf(fmaxf(s1, 0.f));
    Pt[((size_t)bb * 100 + t4 + 2) * 128 + oc] = f2bf(fmaxf(s2, 0.f));
    Pt[((size_t)bb * 100 + t4 + 3) * 128 + oc] = f2bf(fmaxf(s3, 0.f));
  }
}

// fused start/end 1x1 conv 256->1 + sigmoid
__global__ void conv1x1_sig_dual(const float* __restrict__ s1, const float* __restrict__ e1,
                                 const float* __restrict__ ws2, const float* __restrict__ bs2,
                                 const float* __restrict__ we2, const float* __restrict__ be2,
                                 float* __restrict__ out) {
  int t = threadIdx.x;
  if (t >= 100) return;
  int idx = blockIdx.x, bb = idx & 3, sel = idx >> 2;
  const float* in = sel ? e1 : s1;
  const float* w = sel ? we2 : ws2;
  float s = sel ? be2[0] : bs2[0];
  #pragma unroll 8
  for (int c = 0; c < 256; ++c) s += w[c] * in[((size_t)bb * 256 + c) * 100 + t];
  out[80000 + sel * 400 + bb * 100 + t] = sigmoidf_(s);
}

// ---------- fused prep: castw + cast_wq + invperm + tileinfo + zero-page ----------
__global__ void prep_fused(const float* __restrict__ w2a, const float* __restrict__ w2b,
                           const float* __restrict__ w2c, u16* __restrict__ w2a_bf,
                           u16* __restrict__ w2b_pk, u16* __restrict__ w2c_pk,
                           const float* __restrict__ w3d, u16* __restrict__ Wq,
                           int* __restrict__ invperm, int* __restrict__ tinfo,
                           int* __restrict__ order, u16* __restrict__ zp) {
  int bid = blockIdx.x, tid = threadIdx.x;
  if (bid < 576) {
    int i = bid * 256 + tid;
    if (i < 65536) w2a_bf[i] = f2bf(w2a[i]);
    if (i < 147456) {
      int oc = i / 1152, r = i % 1152, kk = r >> 7, ic = r & 127;
      int src = (oc * 128 + ic) * 9 + kk;
      w2b_pk[i] = f2bf(w2b[src]);
      w2c_pk[i] = f2bf(w2c[src]);
    }
  } else if (bid < 640) {
    int u = (bid - 576) * 256 + tid;  // 16384 threads
    int o = u >> 5, n = u & 31;
    const float* src = w3d + (size_t)o * 4096 + n;
    u16* dst = Wq + (size_t)u * 128;
    for (int c0 = 0; c0 < 128; c0 += 8) {
      __align__(16) u16 h[8];
      #pragma unroll
      for (int j = 0; j < 8; ++j) h[j] = f2bf(src[(size_t)(c0 + j) * 32]);
      *(uint4*)(dst + c0) = *(const uint4*)h;
    }
  } else if (bid < 680) {
    int p = (bid - 640) * 256 + tid;
    if (p < 10000) invperm[col_rank(p)] = p;
  } else {
    if (tid < 128) zp[tid] = 0;
    __shared__ int C[128];
    int t = tid;
    int kbmin = 0, cnt = 0;
    if (t < 79) {
      int rlo = t * 128;
      int rhi = rlo + 128;
      if (rhi > 5050) rhi = 5050;
      if (rlo < 5050) {
        int s = 0;
        while (100 * (s + 1) - ((s + 1) * s) / 2 <= rlo) ++s;
        int cum = 100 * s - (s * (s - 1)) / 2;
        int tmin = 100, tmax = -1;
        for (int r = rlo; r < rhi; ++r) {
          while (r - cum >= 100 - s) { ++s; cum = 100 * s - (s * (s - 1)) / 2; }
          int e = s + (r - cum);
          float L = (float)(e - s + 2);
          float sp2 = (float)s - 0.5f * L;
          float ep2 = (float)(e + 1) + 0.5f * L;
          int a = (int)floorf(sp2) - 1;
          if (a < 0) a = 0;
          int b = (int)floorf(ep2) + 2;
          if (b > 99) b = 99;
          if (a < tmin) tmin = a;
          if (b > tmax) tmax = b;
        }
        kbmin = tmin >> 1;
        cnt = (tmax >> 1) - kbmin + 1;
      }
      tinfo[2 * t] = kbmin;
      tinfo[2 * t + 1] = cnt;
    }
    if (t < 128) C[t] = (t < 79) ? cnt : -1;
    __syncthreads();
    if (t < 79) {
      int pos = 0;
      int ct = C[t];
      for (int u = 0; u < 79; ++u) {
        int cu = C[u];
        pos += (cu > ct) || (cu == ct && u < t);
      }
      order[pos] = t;
    }
  }
}

// ---------- analytic mask fill (float64, replica of the Python reference) ----------
__global__ void mask_fill(const int* __restrict__ invperm, u16* __restrict__ Mt) {
  int u = blockIdx.x * 256 + threadIdx.x;
  int r = u >> 5, n = u & 31;
  if (r >= 5050) return;
  int p = invperm[r];
  int s = p / 100, e = p - s * 100;
  double sp = (double)s, ep = (double)(e + 1);
  double L = ep - sp + 1.0;
  double sp2 = sp - L * 0.5;
  double ep2 = ep + L * 0.5;
  double step = (ep2 - sp2) / 95.0;
  double win[8];
  #pragma unroll
  for (int k = 0; k < 8; ++k) win[k] = 0.0;
  int base = -1;
  #pragma unroll
  for (int jj = 0; jj < 3; ++jj) {
    double pos = sp2 + step * (double)(n * 3 + jj);
    double ip;
    double fr = modf(pos, &ip);
    int it = (int)ip;
    if (it >= 0 && it < 99) {
      if (base < 0) base = it;
      int off = it - base;
      win[off] += (1.0 - fr) / 3.0;
      win[off + 1] += fr / 3.0;
    }
  }
  if (base >= 0) {
    u16* dst = Mt + (size_t)r * 3200 + n;
    #pragma unroll
    for (int k = 0; k < 8; ++k) {
      int t = base + k;
      if (t < 100) dst[(size_t)t * 32] = f2bf((float)win[k]);
    }
  }
}

// ---------- shared MFMA pieces (T2 XOR-swizzled reads; sources pre-swizzled) ----------
template<int MI>
__device__ __forceinline__ void mfma_stepT(const u16* As, const u16* Bs, int l, int wm, int wn,
                                           f32x4 (&acc)[MI][4]) {
  int m15 = l & 15, q = l >> 4, sw = m15 & 7;
  #pragma unroll
  for (int kk = 0; kk < 2; ++kk) {
    int koff = ((kk * 4 + q) ^ sw) * 8;
    bf16x8 av[MI], bv[4];
    #pragma unroll
    for (int i = 0; i < MI; ++i)
      av[i] = *(const bf16x8*)(As + (size_t)(wm * (MI * 16) + i * 16 + m15) * 64 + koff);
    #pragma unroll
    for (int j = 0; j < 4; ++j)
      bv[j] = *(const bf16x8*)(Bs + (size_t)(wn * 64 + j * 16 + m15) * 64 + koff);
    #pragma unroll
    for (int i = 0; i < MI; ++i) {
      #pragma unroll
      for (int j = 0; j < 4; ++j)
        acc[i][j] = __builtin_amdgcn_mfma_f32_16x16x32_bf16(av[i], bv[j], acc[i][j], 0, 0, 0);
    }
  }
}

template<int MI>
__device__ __forceinline__ void epilogue_storeT(f32x4 (&acc)[MI][4], u16* OUT,
                                                const float* bias, int row0, int col0, int l,
                                                int wm, int wn, int N, int OC, long long NPB,
                                                const int* colmap) {
  int r4 = (l >> 4) * 4, c1 = l & 15;
  int cols[4], pcols[4];
  #pragma unroll
  for (int j = 0; j < 4; ++j) {
    cols[j] = col0 + wn * 64 + j * 16 + c1;
    pcols[j] = (cols[j] < N) ? (colmap ? colmap[cols[j]] : cols[j]) : 0;
  }
  #pragma unroll
  for (int i = 0; i < MI; ++i) {
    int row = row0 + wm * (MI * 16) + i * 16 + r4;
    int ob = row % OC;
    size_t obb = (size_t)(row / OC) * (size_t)OC * (size_t)NPB;
    float b0 = bias[ob + 0], b1 = bias[ob + 1], b2 = bias[ob + 2], b3 = bias[ob + 3];
    #pragma unroll
    for (int j = 0; j < 4; ++j) {
      if (cols[j] < N) {
        f32x4 v = acc[i][j];
        __align__(8) u16 h[4];
        h[0] = f2bf(fmaxf(v[0] + b0, 0.f));
        h[1] = f2bf(fmaxf(v[1] + b1, 0.f));
        h[2] = f2bf(fmaxf(v[2] + b2, 0.f));
        h[3] = f2bf(fmaxf(v[3] + b3, 0.f));
        *(uint2*)(OUT + obb + (size_t)pcols[j] * OC + ob) = *(const uint2*)h;
      }
    }
  }
}

// ---------- generic BT-GEMM; single-buffer 2-barrier loop (m97 structure) ----------
__global__ __launch_bounds__(256, 2) void gemm_bt(const u16* __restrict__ A,
                                                  const u16* __restrict__ B,
                                                  u16* __restrict__ OUT,
                                                  const float* __restrict__ bias, int N, int K,
                                                  const int* __restrict__ tinfo,
                                                  const int* __restrict__ order, int kblocks,
                                                  int OC, long long NPB, int NclampB,
                                                  const int* __restrict__ colmap, int mt0) {
  __shared__ __align__(16) u16 As[128 * 64];
  __shared__ __align__(16) u16 Bs[128 * 64];
  int mt = mt0 + blockIdx.x;
  int nt = order ? order[blockIdx.y] : blockIdx.y;
  int col0 = nt * 128, row0 = mt * 128;
  int tid = threadIdx.x, w = tid >> 6, l = tid & 63;
  int wm = w >> 1, wn = w & 1;
  int lr = l >> 3;
  int lk_sw = ((l & 7) ^ lr) * 8;
  f32x4 acc[4][4] = {};
  size_t aoff[4];
  size_t boff[4];
  #pragma unroll
  for (int r = 0; r < 4; ++r) {
    int chunk = r * 4 + w;
    int rowA = row0 + chunk * 8 + lr;
    aoff[r] = (size_t)rowA * K + lk_sw;
    int colB = col0 + chunk * 8 + lr;
    if (colB >= NclampB) colB = NclampB - 1;
    boff[r] = (size_t)colB * K + lk_sw;
  }
  int kbmin = 0, cnt = kblocks;
  if (tinfo) { kbmin = tinfo[2 * nt]; cnt = tinfo[2 * nt + 1]; }
  for (int i = 0; i < cnt; ++i) {
    int k0 = (kbmin + i) * 64;
    #pragma unroll
    for (int r = 0; r < 4; ++r) {
      int chunk = r * 4 + w;
      glds16(A + aoff[r] + k0, As + chunk * 512);
      glds16(B + boff[r] + k0, Bs + chunk * 512);
    }
    __syncthreads();
    mfma_stepT<4>(As, Bs, l, wm, wn, acc);
    __syncthreads();
  }
  epilogue_storeT<4>(acc, OUT, bias, row0, col0, l, wm, wn, N, OC, NPB, colmap);
}

// ---------- qprep as MFMA GEMM ----------
__global__ __launch_bounds__(256, 2) void qprep_mfma(const u16* __restrict__ Wq,
                                                     const u16* __restrict__ Pt,
                                                     u16* __restrict__ Qb) {
  __shared__ __align__(16) u16 As[128 * 64];
  __shared__ __align__(16) u16 Bs[128 * 64];
  int mt = blockIdx.x, nt = blockIdx.y;
  int col0 = nt * 128, row0 = mt * 128;
  int tid = threadIdx.x, w = tid >> 6, l = tid & 63;
  int wm = w >> 1, wn = w & 1;
  int lr = l >> 3;
  int lk_sw = ((l & 7) ^ lr) * 8;
  f32x4 acc[4][4] = {};
  size_t aoff[4];
  size_t boff[4];
  #pragma unroll
  for (int r = 0; r < 4; ++r) {
    int chunk = r * 4 + w;
    int rowA = row0 + chunk * 8 + lr;
    aoff[r] = (size_t)rowA * 128 + lk_sw;
    int colB = col0 + chunk * 8 + lr;
    if (colB >= 400) colB = 399;
    boff[r] = (size_t)colB * 128 + lk_sw;
  }
  #pragma unroll
  for (int kb = 0; kb < 2; ++kb) {
    int k0 = kb * 64;
    #pragma unroll
    for (int r = 0; r < 4; ++r) {
      int chunk = r * 4 + w;
      glds16(Wq + aoff[r] + k0, As + chunk * 512);
      glds16(Pt + boff[r] + k0, Bs + chunk * 512);
    }
    __syncthreads();
    mfma_stepT<4>(As, Bs, l, wm, wn, acc);
    __syncthreads();
  }
  int r4 = (l >> 4) * 4, c1 = l & 15;
  #pragma unroll
  for (int i = 0; i < 4; ++i) {
    int row = row0 + wm * 64 + i * 16 + r4;
    int o = row >> 5, n = row & 31;
    #pragma unroll
    for (int j = 0; j < 4; ++j) {
      int col = col0 + wn * 64 + j * 16 + c1;
      if (col < 400) {
        int b = col / 100, t = col - b * 100;
        f32x4 v = acc[i][j];
        __align__(8) u16 h[4];
        h[0] = f2bf(v[0]);
        h[1] = f2bf(v[1]);
        h[2] = f2bf(v[2]);
        h[3] = f2bf(v[3]);
        *(uint2*)(Qb + ((size_t)(b * 512 + o)) * 3200 + t * 32 + n) = *(const uint2*)h;
      }
    }
  }
}

// ---------- 3x3 conv as shifted BT-GEMM ----------
__global__ __launch_bounds__(256, 2) void conv3x3_gemm(const u16* __restrict__ Apk,
                                                       const u16* __restrict__ X,
                                                       u16* __restrict__ OUT,
                                                       const float* __restrict__ bias,
                                                       const u16* __restrict__ zp) {
  __shared__ __align__(16) u16 As[128 * 64];
  __shared__ __align__(16) u16 Bs[128 * 64];
  int nt = blockIdx.x;
  int col0 = nt * 128;
  int tid = threadIdx.x, w = tid >> 6, l = tid & 63;
  int wm = w >> 1, wn = w & 1;
  int lr = l >> 3;
  int lk_sw = ((l & 7) ^ lr) * 8;
  int cj[4], yy[4], xx[4];
  bool vv[4];
  size_t aoff[4];
  #pragma unroll
  for (int r = 0; r < 4; ++r) {
    int chunk = r * 4 + w;
    int c = col0 + chunk * 8 + lr;
    cj[r] = c;
    vv[r] = (c < 40000);
    int p = c % 10000;
    yy[r] = p / 100;
    xx[r] = p % 100;
    aoff[r] = (size_t)(chunk * 8 + lr) * 1152 + lk_sw;
  }
  f32x4 acc[4][4] = {};
  for (int s = 0; s < 9; ++s) {
    int dy = s / 3 - 1, dx = s % 3 - 1;
    int doff = dy * 100 + dx;
    #pragma unroll
    for (int half = 0; half < 2; ++half) {
      int k0 = s * 128 + half * 64;
      int c0 = half * 64;
      #pragma unroll
      for (int r = 0; r < 4; ++r) {
        int chunk = r * 4 + w;
        glds16(Apk + aoff[r] + k0, As + chunk * 512);
        int y2 = yy[r] + dy, x2 = xx[r] + dx;
        bool ok = vv[r] && ((unsigned)y2 < 100u) && ((unsigned)x2 < 100u);
        const u16* src = ok ? (X + (size_t)(cj[r] + doff) * 128 + c0 + lk_sw) : zp;
        glds16(src, Bs + chunk * 512);
      }
      __syncthreads();
      mfma_stepT<4>(As, Bs, l, wm, wn, acc);
      __syncthreads();
    }
  }
  epilogue_storeT<4>(acc, OUT, bias, 0, col0, l, wm, wn, 40000, 128, 40000LL, nullptr);
}

// ---------- final head ----------
__global__ void head_conf(const u16* __restrict__ x4t, const float* __restrict__ w2d,
                          const float* __restrict__ b2d, float* __restrict__ out) {
  __shared__ float wS[256];
  int tid = threadIdx.x;
  wS[tid] = w2d[tid];
  __syncthreads();
  int u = blockIdx.x * 256 + tid;
  if (u >= 40000) return;
  int b = u / 10000, pidx = u % 10000;
  const uint4* xr = (const uint4*)(x4t + (size_t)u * 128);
  float s0 = b2d[0], s1 = b2d[1];
  #pragma unroll 4
  for (int v = 0; v < 16; ++v) {
    uint4 q = xr[v];
    int c = v * 8;
    uint32_t d;
    float lo, hi;
    d = q.x; lo = __uint_as_float(d << 16); hi = __uint_as_float(d & 0xffff0000u);
    s0 += wS[c] * lo + wS[c + 1] * hi; s1 += wS[128 + c] * lo + wS[129 + c] * hi;
    d = q.y; lo = __uint_as_float(d << 16); hi = __uint_as_float(d & 0xffff0000u);
    s0 += wS[c + 2] * lo + wS[c + 3] * hi; s1 += wS[130 + c] * lo + wS[131 + c] * hi;
    d = q.z; lo = __uint_as_float(d << 16); hi = __uint_as_float(d & 0xffff0000u);
    s0 += wS[c + 4] * lo + wS[c + 5] * hi; s1 += wS[132 + c] * lo + wS[133 + c] * hi;
    d = q.w; lo = __uint_as_float(d << 16); hi = __uint_as_float(d & 0xffff0000u);
    s0 += wS[c + 6] * lo + wS[c + 7] * hi; s1 += wS[134 + c] * lo + wS[135 + c] * hi;
  }
  out[((size_t)b * 2 + 0) * 10000 + pidx] = sigmoidf_(s0);
  out[((size_t)b * 2 + 1) * 10000 + pidx] = sigmoidf_(s1);
}

// ---------- launch ----------
extern "C" void kernel_launch(void* const* d_in, const int* in_sizes, int n_in, void* d_out,
                              int out_size, void* d_ws, size_t ws_size, hipStream_t stream) {
  const float* inputs = (const float*)d_in[0];
  const float* w_b1 = (const float*)d_in[1];
  const float* b_b1 = (const float*)d_in[2];
  const float* w_b2 = (const float*)d_in[3];
  const float* b_b2 = (const float*)d_in[4];
  const float* w_s1 = (const float*)d_in[5];
  const float* b_s1 = (const float*)d_in[6];
  const float* w_s2 = (const float*)d_in[7];
  const float* b_s2 = (const float*)d_in[8];
  const float* w_e1 = (const float*)d_in[9];
  const float* b_e1 = (const float*)d_in[10];
  const float* w_e2 = (const float*)d_in[11];
  const float* b_e2 = (const float*)d_in[12];
  const float* w_p1 = (const float*)d_in[13];
  const float* b_p1 = (const float*)d_in[14];
  const float* w3d = (const float*)d_in[15];
  const float* b3d = (const float*)d_in[16];
  const float* w2a = (const float*)d_in[17];
  const float* b2a = (const float*)d_in[18];
  const float* w2b = (const float*)d_in[19];
  const float* b2b = (const float*)d_in[20];
  const float* w2c = (const float*)d_in[21];
  const float* b2c = (const float*)d_in[22];
  const float* w2d = (const float*)d_in[23];
  const float* b2d = (const float*)d_in[24];
  float* out = (float*)d_out;
  char* ws = (char*)d_ws;

  int* tinfo = (int*)(ws + 0);
  int* order = (int*)(ws + 2048);
  u16* zp = (u16*)(ws + 16384);
  int* invperm = (int*)(ws + 45056);
  float* base = (float*)(ws + 499712);          // 409600
  float* s1buf = (float*)(ws + 909312);         // 409600
  u16* Pt = (u16*)(ws + 1318912);               // 102400
  u16* w2a_bf = (u16*)(ws + 1421312);           // 131072
  u16* w2b_pk = (u16*)(ws + 1552384);           // 294912
  u16* w2c_pk = (u16*)(ws + 1847296);           // 294912
  u16* Qb = (u16*)(ws + 2142208);               // 13107200
  u16* Mt = (u16*)(ws + 15249408);              // rows 0..5119 used (32.768 MB)
  u16* C1t = (u16*)(ws + 79249408);             // 40960000  (end 120209408)
  float* e1buf = (float*)(ws + 2142208);        // aliases Qb: e1 dead before qprep writes Qb
  u16* Wq = (u16*)(ws + 79249408);              // aliases C1t: dead before G1 writes C1t
  u16* x2t = Qb;   // alias: Qb dead after G1
  u16* x3t = C1t;  // alias: C1t dead after G2
  u16* x4t = Mt;   // alias: Mt dead after G1

  hipMemsetAsync(Mt, 0, (size_t)5120 * 3200 * 2, stream);  // Mt valid region

  // fused prep (weights cast/repack, invperm, tile spans + order, zero page)
  prep_fused<<<681, 256, 0, stream>>>(w2a, w2b, w2c, w2a_bf, w2b_pk, w2c_pk, w3d, Wq,
                                      invperm, tinfo, order, zp);
  // analytic boundary-matching mask, bf16, permuted rows
  mask_fill<<<632, 256, 0, stream>>>(invperm, Mt);

  // front end (fp32 exact): fused conv1+conv2, then branches, then sigmoid heads
  front12<<<dim3(4, 16), 256, 0, stream>>>(inputs, w_b1, b_b1, w_b2, b_b2, base);
  conv1d_branch_v<<<250, 256, 0, stream>>>(base, w_s1, b_s1, w_e1, b_e1, w_p1, b_p1,
                                           s1buf, e1buf, Pt);
  conv1x1_sig_dual<<<8, 128, 0, stream>>>(s1buf, e1buf, w_s2, b_s2, w_e2, b_e2, out);

  // qprep as MFMA GEMM: [16384 x 400 x 128]
  qprep_mfma<<<dim3(128, 4), 256, 0, stream>>>(Wq, Pt, Qb);

  // G1 split in two halves (rows 0-1023 / 1024-2047) for profiling visibility
  gemm_bt<<<dim3(8, 79), 256, 0, stream>>>(Qb, Mt, C1t, b3d, 10000, 3200, tinfo, order, 50,
                                           512, 10000LL, 10000, invperm, 0);
  gemm_bt<<<dim3(8, 79), 256, 0, stream>>>(Qb, Mt, C1t, b3d, 10000, 3200, tinfo, order, 50,
                                           512, 10000LL, 10000, invperm, 8);
  // G2: 1x1 conv 512->128
  gemm_bt<<<dim3(1, 313), 256, 0, stream>>>(w2a_bf, C1t, x2t, b2a, 40000, 512, nullptr,
                                            nullptr, 8, 128, 40000LL, 40000, nullptr, 0);
  // G3/G4: 3x3 convs 128->128
  conv3x3_gemm<<<dim3(313), 256, 0, stream>>>(w2b_pk, x2t, x3t, b2b, zp);
  conv3x3_gemm<<<dim3(313), 256, 0, stream>>>(w2c_pk, x3t, x4t, b2c, zp);
  // head
  head_conf<<<157, 256, 0, stream>>>(x4t, w2d, b2d, out);
}

// Round 10
// 346.567 us; speedup vs baseline: 1.1731x; 1.1731x over previous
//
#include <hip/hip_runtime.h>
#include <cstdint>
#include <cstddef>
#include <math.h>

typedef unsigned short u16;
typedef short bf16x8 __attribute__((ext_vector_type(8)));
typedef float f32x4 __attribute__((ext_vector_type(4)));

// ---------- helpers ----------
__device__ __forceinline__ u16 f2bf(float f) {
  union { float f; uint32_t u; } c; c.f = f;
  uint32_t u = c.u;
  return (u16)((u + 0x7FFFu + ((u >> 16) & 1u)) >> 16);
}
__device__ __forceinline__ float bf2f(u16 h) {
  union { uint32_t u; float f; } c; c.u = ((uint32_t)h) << 16;
  return c.f;
}
__device__ __forceinline__ float sigmoidf_(float x) { return 1.f / (1.f + expf(-x)); }

__device__ __forceinline__ void glds16(const void* g, void* l) {
  __builtin_amdgcn_global_load_lds((const __attribute__((address_space(1))) void*)g,
                                   (__attribute__((address_space(3))) void*)l, 16, 0, 0);
}

// column permutation: valid (s<=e) pairs compacted in natural order, invalid at end
__device__ __forceinline__ int col_rank(int p) {
  int s = p / 100, e = p - s * 100;
  int tri = (s * (s - 1)) >> 1;
  return (e >= s) ? (p - tri - s) : (5050 + tri + e);
}

// ---------- front-end 1D convs, ILP version: 4 t per thread via float4 ----------
__global__ void conv1d_k3v(const float* __restrict__ in, const float* __restrict__ w,
                           const float* __restrict__ bias, float* __restrict__ out,
                           int Cin_total, int Cin_g, int ocPerGroup, int OC) {
  int idx = blockIdx.x * 256 + threadIdx.x;
  int sub = idx % 25;
  int tmp = idx / 25;
  int oc = tmp % OC;
  int bb = tmp / OC;
  if (bb >= 4) return;
  int t4 = sub * 4;
  int g = oc / ocPerGroup;
  const float* ip = in + ((size_t)bb * Cin_total + (size_t)g * Cin_g) * 100 + t4;
  const float* wp = w + (size_t)oc * Cin_g * 3;
  float bs = bias[oc];
  float s0 = bs, s1 = bs, s2 = bs, s3 = bs;
  #pragma unroll 4
  for (int ic = 0; ic < Cin_g; ++ic) {
    const float* r = ip + (size_t)ic * 100;
    float4 a = *(const float4*)r;
    float xm = (t4 > 0) ? r[-1] : 0.f;
    float xp = (t4 < 96) ? r[4] : 0.f;
    float w0 = wp[ic * 3 + 0], w1 = wp[ic * 3 + 1], w2 = wp[ic * 3 + 2];
    s0 += w0 * xm + w1 * a.x + w2 * a.y;
    s1 += w0 * a.x + w1 * a.y + w2 * a.z;
    s2 += w0 * a.y + w1 * a.z + w2 * a.w;
    s3 += w0 * a.z + w1 * a.w + w2 * xp;
  }
  float4 o;
  o.x = fmaxf(s0, 0.f); o.y = fmaxf(s1, 0.f);
  o.z = fmaxf(s2, 0.f); o.w = fmaxf(s3, 0.f);
  *(float4*)(out + ((size_t)bb * OC + oc) * 100 + t4) = o;
}

// fused s1/e1/p branches (all read `base`), ILP version
__global__ void conv1d_branch_v(const float* __restrict__ in, const float* __restrict__ wS,
                                const float* __restrict__ bS, const float* __restrict__ wE,
                                const float* __restrict__ bE, const float* __restrict__ wP,
                                const float* __restrict__ bP, float* __restrict__ outS,
                                float* __restrict__ outE, u16* __restrict__ Pt) {
  int idx = blockIdx.x * 256 + threadIdx.x;
  int sub = idx % 25;
  int tmp = idx / 25;
  int ocx = tmp % 640;
  int bb = tmp / 640;
  if (bb >= 4) return;
  int t4 = sub * 4;
  const float* w;
  const float* bias;
  const float* ip;
  int Cin_g, oc;
  if (ocx < 512) {
    int sel = ocx >> 8;
    oc = ocx & 255;
    w = sel ? wE : wS;
    bias = sel ? bE : bS;
    int g = oc >> 6;
    ip = in + ((size_t)bb * 256 + (size_t)g * 64) * 100 + t4;
    Cin_g = 64;
  } else {
    oc = ocx - 512;
    w = wP;
    bias = bP;
    ip = in + (size_t)bb * 256 * 100 + t4;
    Cin_g = 256;
  }
  const float* wp = w + (size_t)oc * Cin_g * 3;
  float bs = bias[oc];
  float s0 = bs, s1 = bs, s2 = bs, s3 = bs;
  #pragma unroll 4
  for (int ic = 0; ic < Cin_g; ++ic) {
    const float* r = ip + (size_t)ic * 100;
    float4 a = *(const float4*)r;
    float xm = (t4 > 0) ? r[-1] : 0.f;
    float xp = (t4 < 96) ? r[4] : 0.f;
    float w0 = wp[ic * 3 + 0], w1 = wp[ic * 3 + 1], w2 = wp[ic * 3 + 2];
    s0 += w0 * xm + w1 * a.x + w2 * a.y;
    s1 += w0 * a.x + w1 * a.y + w2 * a.z;
    s2 += w0 * a.y + w1 * a.z + w2 * a.w;
    s3 += w0 * a.z + w1 * a.w + w2 * xp;
  }
  if (ocx < 512) {
    float* out = (ocx < 256) ? outS : outE;
    float4 o;
    o.x = fmaxf(s0, 0.f); o.y = fmaxf(s1, 0.f);
    o.z = fmaxf(s2, 0.f); o.w = fmaxf(s3, 0.f);
    *(float4*)(out + ((size_t)bb * 256 + oc) * 100 + t4) = o;
  } else {
    Pt[((size_t)bb * 100 + t4 + 0) * 128 + oc] = f2bf(fmaxf(s0, 0.f));
    Pt[((size_t)bb * 100 + t4 + 1) * 128 + oc] = f2bf(fmaxf(s1, 0.f));
    Pt[((size_t)bb * 100 + t4 + 2) * 128 + oc] = f2bf(fmaxf(s2, 0.f));
    Pt[((size_t)bb * 100 + t4 + 3) * 128 + oc] = f2bf(fmaxf(s3, 0.f));
  }
}

// fused start/end 1x1 conv 256->1 + sigmoid
__global__ void conv1x1_sig_dual(const float* __restrict__ s1, const float* __restrict__ e1,
                                 const float* __restrict__ ws2, const float* __restrict__ bs2,
                                 const float* __restrict__ we2, const float* __restrict__ be2,
                                 float* __restrict__ out) {
  int t = threadIdx.x;
  if (t >= 100) return;
  int idx = blockIdx.x, bb = idx & 3, sel = idx >> 2;
  const float* in = sel ? e1 : s1;
  const float* w = sel ? we2 : ws2;
  float s = sel ? be2[0] : bs2[0];
  #pragma unroll 8
  for (int c = 0; c < 256; ++c) s += w[c] * in[((size_t)bb * 256 + c) * 100 + t];
  out[80000 + sel * 400 + bb * 100 + t] = sigmoidf_(s);
}

// ---------- fused prep: castw + cast_wq + invperm + tileinfo + zero-page ----------
__global__ void prep_fused(const float* __restrict__ w2a, const float* __restrict__ w2b,
                           const float* __restrict__ w2c, u16* __restrict__ w2a_bf,
                           u16* __restrict__ w2b_pk, u16* __restrict__ w2c_pk,
                           const float* __restrict__ w3d, u16* __restrict__ Wq,
                           int* __restrict__ invperm, int* __restrict__ tinfo,
                           int* __restrict__ order, u16* __restrict__ zp) {
  int bid = blockIdx.x, tid = threadIdx.x;
  if (bid < 576) {
    int i = bid * 256 + tid;
    if (i < 65536) w2a_bf[i] = f2bf(w2a[i]);
    if (i < 147456) {
      int oc = i / 1152, r = i % 1152, kk = r >> 7, ic = r & 127;
      int src = (oc * 128 + ic) * 9 + kk;
      w2b_pk[i] = f2bf(w2b[src]);
      w2c_pk[i] = f2bf(w2c[src]);
    }
  } else if (bid < 640) {
    int u = (bid - 576) * 256 + tid;  // 16384 threads
    int o = u >> 5, n = u & 31;
    const float* src = w3d + (size_t)o * 4096 + n;
    u16* dst = Wq + (size_t)u * 128;
    for (int c0 = 0; c0 < 128; c0 += 8) {
      __align__(16) u16 h[8];
      #pragma unroll
      for (int j = 0; j < 8; ++j) h[j] = f2bf(src[(size_t)(c0 + j) * 32]);
      *(uint4*)(dst + c0) = *(const uint4*)h;
    }
  } else if (bid < 680) {
    int p = (bid - 640) * 256 + tid;
    if (p < 10000) invperm[col_rank(p)] = p;
  } else {
    if (tid < 128) zp[tid] = 0;
    __shared__ int C[128];
    int t = tid;
    int kbmin = 0, cnt = 0;
    if (t < 79) {
      int rlo = t * 128;
      int rhi = rlo + 128;
      if (rhi > 5050) rhi = 5050;
      if (rlo < 5050) {
        int s = 0;
        while (100 * (s + 1) - ((s + 1) * s) / 2 <= rlo) ++s;
        int cum = 100 * s - (s * (s - 1)) / 2;
        int tmin = 100, tmax = -1;
        for (int r = rlo; r < rhi; ++r) {
          while (r - cum >= 100 - s) { ++s; cum = 100 * s - (s * (s - 1)) / 2; }
          int e = s + (r - cum);
          float L = (float)(e - s + 2);
          float sp2 = (float)s - 0.5f * L;
          float ep2 = (float)(e + 1) + 0.5f * L;
          int a = (int)floorf(sp2) - 1;
          if (a < 0) a = 0;
          int b = (int)floorf(ep2) + 2;
          if (b > 99) b = 99;
          if (a < tmin) tmin = a;
          if (b > tmax) tmax = b;
        }
        kbmin = tmin >> 1;
        cnt = (tmax >> 1) - kbmin + 1;
      }
      tinfo[2 * t] = kbmin;
      tinfo[2 * t + 1] = cnt;
    }
    if (t < 128) C[t] = (t < 79) ? cnt : -1;
    __syncthreads();
    if (t < 79) {
      int pos = 0;
      int ct = C[t];
      for (int u = 0; u < 79; ++u) {
        int cu = C[u];
        pos += (cu > ct) || (cu == ct && u < t);
      }
      order[pos] = t;
    }
  }
}

// ---------- analytic mask fill (float64, replica of the Python reference) ----------
__global__ void mask_fill(const int* __restrict__ invperm, u16* __restrict__ Mt) {
  int u = blockIdx.x * 256 + threadIdx.x;
  int r = u >> 5, n = u & 31;
  if (r >= 5050) return;
  int p = invperm[r];
  int s = p / 100, e = p - s * 100;
  double sp = (double)s, ep = (double)(e + 1);
  double L = ep - sp + 1.0;
  double sp2 = sp - L * 0.5;
  double ep2 = ep + L * 0.5;
  double step = (ep2 - sp2) / 95.0;
  double win[8];
  #pragma unroll
  for (int k = 0; k < 8; ++k) win[k] = 0.0;
  int base = -1;
  #pragma unroll
  for (int jj = 0; jj < 3; ++jj) {
    double pos = sp2 + step * (double)(n * 3 + jj);
    double ip;
    double fr = modf(pos, &ip);
    int it = (int)ip;
    if (it >= 0 && it < 99) {
      if (base < 0) base = it;
      int off = it - base;
      win[off] += (1.0 - fr) / 3.0;
      win[off + 1] += fr / 3.0;
    }
  }
  if (base >= 0) {
    u16* dst = Mt + (size_t)r * 3200 + n;
    #pragma unroll
    for (int k = 0; k < 8; ++k) {
      int t = base + k;
      if (t < 100) dst[(size_t)t * 32] = f2bf((float)win[k]);
    }
  }
}

// ---------- shared MFMA pieces (T2 XOR-swizzled reads; sources pre-swizzled) ----------
template<int MI>
__device__ __forceinline__ void mfma_stepT(const u16* As, const u16* Bs, int l, int wm, int wn,
                                           f32x4 (&acc)[MI][4]) {
  int m15 = l & 15, q = l >> 4, sw = m15 & 7;
  #pragma unroll
  for (int kk = 0; kk < 2; ++kk) {
    int koff = ((kk * 4 + q) ^ sw) * 8;
    bf16x8 av[MI], bv[4];
    #pragma unroll
    for (int i = 0; i < MI; ++i)
      av[i] = *(const bf16x8*)(As + (size_t)(wm * (MI * 16) + i * 16 + m15) * 64 + koff);
    #pragma unroll
    for (int j = 0; j < 4; ++j)
      bv[j] = *(const bf16x8*)(Bs + (size_t)(wn * 64 + j * 16 + m15) * 64 + koff);
    #pragma unroll
    for (int i = 0; i < MI; ++i) {
      #pragma unroll
      for (int j = 0; j < 4; ++j)
        acc[i][j] = __builtin_amdgcn_mfma_f32_16x16x32_bf16(av[i], bv[j], acc[i][j], 0, 0, 0);
    }
  }
}

template<int MI>
__device__ __forceinline__ void epilogue_storeT(f32x4 (&acc)[MI][4], u16* OUT,
                                                const float* bias, int row0, int col0, int l,
                                                int wm, int wn, int N, int OC, long long NPB,
                                                const int* colmap) {
  int r4 = (l >> 4) * 4, c1 = l & 15;
  int cols[4], pcols[4];
  #pragma unroll
  for (int j = 0; j < 4; ++j) {
    cols[j] = col0 + wn * 64 + j * 16 + c1;
    pcols[j] = (cols[j] < N) ? (colmap ? colmap[cols[j]] : cols[j]) : 0;
  }
  #pragma unroll
  for (int i = 0; i < MI; ++i) {
    int row = row0 + wm * (MI * 16) + i * 16 + r4;
    int ob = row % OC;
    size_t obb = (size_t)(row / OC) * (size_t)OC * (size_t)NPB;
    float b0 = bias[ob + 0], b1 = bias[ob + 1], b2 = bias[ob + 2], b3 = bias[ob + 3];
    #pragma unroll
    for (int j = 0; j < 4; ++j) {
      if (cols[j] < N) {
        f32x4 v = acc[i][j];
        __align__(8) u16 h[4];
        h[0] = f2bf(fmaxf(v[0] + b0, 0.f));
        h[1] = f2bf(fmaxf(v[1] + b1, 0.f));
        h[2] = f2bf(fmaxf(v[2] + b2, 0.f));
        h[3] = f2bf(fmaxf(v[3] + b3, 0.f));
        *(uint2*)(OUT + obb + (size_t)pcols[j] * OC + ob) = *(const uint2*)h;
      }
    }
  }
}

// ---------- generic BT-GEMM; single-buffer 2-barrier loop (m97 structure) ----------
__global__ __launch_bounds__(256, 2) void gemm_bt(const u16* __restrict__ A,
                                                  const u16* __restrict__ B,
                                                  u16* __restrict__ OUT,
                                                  const float* __restrict__ bias, int N, int K,
                                                  const int* __restrict__ tinfo,
                                                  const int* __restrict__ order, int kblocks,
                                                  int OC, long long NPB, int NclampB,
                                                  const int* __restrict__ colmap, int mt0) {
  __shared__ __align__(16) u16 As[128 * 64];
  __shared__ __align__(16) u16 Bs[128 * 64];
  int mt = mt0 + blockIdx.x;
  int nt = order ? order[blockIdx.y] : blockIdx.y;
  int col0 = nt * 128, row0 = mt * 128;
  int tid = threadIdx.x, w = tid >> 6, l = tid & 63;
  int wm = w >> 1, wn = w & 1;
  int lr = l >> 3;
  int lk_sw = ((l & 7) ^ lr) * 8;
  f32x4 acc[4][4] = {};
  size_t aoff[4];
  size_t boff[4];
  #pragma unroll
  for (int r = 0; r < 4; ++r) {
    int chunk = r * 4 + w;
    int rowA = row0 + chunk * 8 + lr;
    aoff[r] = (size_t)rowA * K + lk_sw;
    int colB = col0 + chunk * 8 + lr;
    if (colB >= NclampB) colB = NclampB - 1;
    boff[r] = (size_t)colB * K + lk_sw;
  }
  int kbmin = 0, cnt = kblocks;
  if (tinfo) { kbmin = tinfo[2 * nt]; cnt = tinfo[2 * nt + 1]; }
  for (int i = 0; i < cnt; ++i) {
    int k0 = (kbmin + i) * 64;
    #pragma unroll
    for (int r = 0; r < 4; ++r) {
      int chunk = r * 4 + w;
      glds16(A + aoff[r] + k0, As + chunk * 512);
      glds16(B + boff[r] + k0, Bs + chunk * 512);
    }
    __syncthreads();
    mfma_stepT<4>(As, Bs, l, wm, wn, acc);
    __syncthreads();
  }
  epilogue_storeT<4>(acc, OUT, bias, row0, col0, l, wm, wn, N, OC, NPB, colmap);
}

// ---------- qprep as MFMA GEMM ----------
__global__ __launch_bounds__(256, 2) void qprep_mfma(const u16* __restrict__ Wq,
                                                     const u16* __restrict__ Pt,
                                                     u16* __restrict__ Qb) {
  __shared__ __align__(16) u16 As[128 * 64];
  __shared__ __align__(16) u16 Bs[128 * 64];
  int mt = blockIdx.x, nt = blockIdx.y;
  int col0 = nt * 128, row0 = mt * 128;
  int tid = threadIdx.x, w = tid >> 6, l = tid & 63;
  int wm = w >> 1, wn = w & 1;
  int lr = l >> 3;
  int lk_sw = ((l & 7) ^ lr) * 8;
  f32x4 acc[4][4] = {};
  size_t aoff[4];
  size_t boff[4];
  #pragma unroll
  for (int r = 0; r < 4; ++r) {
    int chunk = r * 4 + w;
    int rowA = row0 + chunk * 8 + lr;
    aoff[r] = (size_t)rowA * 128 + lk_sw;
    int colB = col0 + chunk * 8 + lr;
    if (colB >= 400) colB = 399;
    boff[r] = (size_t)colB * 128 + lk_sw;
  }
  #pragma unroll
  for (int kb = 0; kb < 2; ++kb) {
    int k0 = kb * 64;
    #pragma unroll
    for (int r = 0; r < 4; ++r) {
      int chunk = r * 4 + w;
      glds16(Wq + aoff[r] + k0, As + chunk * 512);
      glds16(Pt + boff[r] + k0, Bs + chunk * 512);
    }
    __syncthreads();
    mfma_stepT<4>(As, Bs, l, wm, wn, acc);
    __syncthreads();
  }
  int r4 = (l >> 4) * 4, c1 = l & 15;
  #pragma unroll
  for (int i = 0; i < 4; ++i) {
    int row = row0 + wm * 64 + i * 16 + r4;
    int o = row >> 5, n = row & 31;
    #pragma unroll
    for (int j = 0; j < 4; ++j) {
      int col = col0 + wn * 64 + j * 16 + c1;
      if (col < 400) {
        int b = col / 100, t = col - b * 100;
        f32x4 v = acc[i][j];
        __align__(8) u16 h[4];
        h[0] = f2bf(v[0]);
        h[1] = f2bf(v[1]);
        h[2] = f2bf(v[2]);
        h[3] = f2bf(v[3]);
        *(uint2*)(Qb + ((size_t)(b * 512 + o)) * 3200 + t * 32 + n) = *(const uint2*)h;
      }
    }
  }
}

// ---------- 3x3 conv as shifted BT-GEMM ----------
__global__ __launch_bounds__(256, 2) void conv3x3_gemm(const u16* __restrict__ Apk,
                                                       const u16* __restrict__ X,
                                                       u16* __restrict__ OUT,
                                                       const float* __restrict__ bias,
                                                       const u16* __restrict__ zp) {
  __shared__ __align__(16) u16 As[128 * 64];
  __shared__ __align__(16) u16 Bs[128 * 64];
  int nt = blockIdx.x;
  int col0 = nt * 128;
  int tid = threadIdx.x, w = tid >> 6, l = tid & 63;
  int wm = w >> 1, wn = w & 1;
  int lr = l >> 3;
  int lk_sw = ((l & 7) ^ lr) * 8;
  int cj[4], yy[4], xx[4];
  bool vv[4];
  size_t aoff[4];
  #pragma unroll
  for (int r = 0; r < 4; ++r) {
    int chunk = r * 4 + w;
    int c = col0 + chunk * 8 + lr;
    cj[r] = c;
    vv[r] = (c < 40000);
    int p = c % 10000;
    yy[r] = p / 100;
    xx[r] = p % 100;
    aoff[r] = (size_t)(chunk * 8 + lr) * 1152 + lk_sw;
  }
  f32x4 acc[4][4] = {};
  for (int s = 0; s < 9; ++s) {
    int dy = s / 3 - 1, dx = s % 3 - 1;
    int doff = dy * 100 + dx;
    #pragma unroll
    for (int half = 0; half < 2; ++half) {
      int k0 = s * 128 + half * 64;
      int c0 = half * 64;
      #pragma unroll
      for (int r = 0; r < 4; ++r) {
        int chunk = r * 4 + w;
        glds16(Apk + aoff[r] + k0, As + chunk * 512);
        int y2 = yy[r] + dy, x2 = xx[r] + dx;
        bool ok = vv[r] && ((unsigned)y2 < 100u) && ((unsigned)x2 < 100u);
        const u16* src = ok ? (X + (size_t)(cj[r] + doff) * 128 + c0 + lk_sw) : zp;
        glds16(src, Bs + chunk * 512);
      }
      __syncthreads();
      mfma_stepT<4>(As, Bs, l, wm, wn, acc);
      __syncthreads();
    }
  }
  epilogue_storeT<4>(acc, OUT, bias, 0, col0, l, wm, wn, 40000, 128, 40000LL, nullptr);
}

// ---------- final head ----------
__global__ void head_conf(const u16* __restrict__ x4t, const float* __restrict__ w2d,
                          const float* __restrict__ b2d, float* __restrict__ out) {
  __shared__ float wS[256];
  int tid = threadIdx.x;
  wS[tid] = w2d[tid];
  __syncthreads();
  int u = blockIdx.x * 256 + tid;
  if (u >= 40000) return;
  int b = u / 10000, pidx = u % 10000;
  const uint4* xr = (const uint4*)(x4t + (size_t)u * 128);
  float s0 = b2d[0], s1 = b2d[1];
  #pragma unroll 4
  for (int v = 0; v < 16; ++v) {
    uint4 q = xr[v];
    int c = v * 8;
    uint32_t d;
    float lo, hi;
    d = q.x; lo = __uint_as_float(d << 16); hi = __uint_as_float(d & 0xffff0000u);
    s0 += wS[c] * lo + wS[c + 1] * hi; s1 += wS[128 + c] * lo + wS[129 + c] * hi;
    d = q.y; lo = __uint_as_float(d << 16); hi = __uint_as_float(d & 0xffff0000u);
    s0 += wS[c + 2] * lo + wS[c + 3] * hi; s1 += wS[130 + c] * lo + wS[131 + c] * hi;
    d = q.z; lo = __uint_as_float(d << 16); hi = __uint_as_float(d & 0xffff0000u);
    s0 += wS[c + 4] * lo + wS[c + 5] * hi; s1 += wS[132 + c] * lo + wS[133 + c] * hi;
    d = q.w; lo = __uint_as_float(d << 16); hi = __uint_as_float(d & 0xffff0000u);
    s0 += wS[c + 6] * lo + wS[c + 7] * hi; s1 += wS[134 + c] * lo + wS[135 + c] * hi;
  }
  out[((size_t)b * 2 + 0) * 10000 + pidx] = sigmoidf_(s0);
  out[((size_t)b * 2 + 1) * 10000 + pidx] = sigmoidf_(s1);
}

// ---------- launch ----------
extern "C" void kernel_launch(void* const* d_in, const int* in_sizes, int n_in, void* d_out,
                              int out_size, void* d_ws, size_t ws_size, hipStream_t stream) {
  const float* inputs = (const float*)d_in[0];
  const float* w_b1 = (const float*)d_in[1];
  const float* b_b1 = (const float*)d_in[2];
  const float* w_b2 = (const float*)d_in[3];
  const float* b_b2 = (const float*)d_in[4];
  const float* w_s1 = (const float*)d_in[5];
  const float* b_s1 = (const float*)d_in[6];
  const float* w_s2 = (const float*)d_in[7];
  const float* b_s2 = (const float*)d_in[8];
  const float* w_e1 = (const float*)d_in[9];
  const float* b_e1 = (const float*)d_in[10];
  const float* w_e2 = (const float*)d_in[11];
  const float* b_e2 = (const float*)d_in[12];
  const float* w_p1 = (const float*)d_in[13];
  const float* b_p1 = (const float*)d_in[14];
  const float* w3d = (const float*)d_in[15];
  const float* b3d = (const float*)d_in[16];
  const float* w2a = (const float*)d_in[17];
  const float* b2a = (const float*)d_in[18];
  const float* w2b = (const float*)d_in[19];
  const float* b2b = (const float*)d_in[20];
  const float* w2c = (const float*)d_in[21];
  const float* b2c = (const float*)d_in[22];
  const float* w2d = (const float*)d_in[23];
  const float* b2d = (const float*)d_in[24];
  float* out = (float*)d_out;
  char* ws = (char*)d_ws;

  int* tinfo = (int*)(ws + 0);
  int* order = (int*)(ws + 2048);
  u16* zp = (u16*)(ws + 16384);
  int* invperm = (int*)(ws + 45056);
  float* base1 = (float*)(ws + 90112);          // 409600
  float* base = (float*)(ws + 499712);          // 409600
  float* s1buf = (float*)(ws + 909312);         // 409600
  u16* Pt = (u16*)(ws + 1318912);               // 102400
  u16* w2a_bf = (u16*)(ws + 1421312);           // 131072
  u16* w2b_pk = (u16*)(ws + 1552384);           // 294912
  u16* w2c_pk = (u16*)(ws + 1847296);           // 294912
  u16* Qb = (u16*)(ws + 2142208);               // 13107200
  u16* Mt = (u16*)(ws + 15249408);              // rows 0..5119 used (32.768 MB)
  u16* C1t = (u16*)(ws + 79249408);             // 40960000  (end 120209408)
  float* e1buf = (float*)(ws + 2142208);        // aliases Qb: e1 dead before qprep writes Qb
  u16* Wq = (u16*)(ws + 79249408);              // aliases C1t: dead before G1 writes C1t
  u16* x2t = Qb;   // alias: Qb dead after G1
  u16* x3t = C1t;  // alias: C1t dead after G2
  u16* x4t = Mt;   // alias: Mt dead after G1

  hipMemsetAsync(Mt, 0, (size_t)5120 * 3200 * 2, stream);  // Mt valid region

  // fused prep (weights cast/repack, invperm, tile spans + order, zero page)
  prep_fused<<<681, 256, 0, stream>>>(w2a, w2b, w2c, w2a_bf, w2b_pk, w2c_pk, w3d, Wq,
                                      invperm, tinfo, order, zp);
  // analytic boundary-matching mask, bf16, permuted rows
  mask_fill<<<632, 256, 0, stream>>>(invperm, Mt);

  // front end (fp32 exact, ILP-vectorized)
  conv1d_k3v<<<100, 256, 0, stream>>>(inputs, w_b1, b_b1, base1, 400, 100, 64, 256);
  conv1d_k3v<<<100, 256, 0, stream>>>(base1, w_b2, b_b2, base, 256, 64, 64, 256);
  conv1d_branch_v<<<250, 256, 0, stream>>>(base, w_s1, b_s1, w_e1, b_e1, w_p1, b_p1,
                                           s1buf, e1buf, Pt);
  conv1x1_sig_dual<<<8, 128, 0, stream>>>(s1buf, e1buf, w_s2, b_s2, w_e2, b_e2, out);

  // qprep as MFMA GEMM: [16384 x 400 x 128]
  qprep_mfma<<<dim3(128, 4), 256, 0, stream>>>(Wq, Pt, Qb);

  // G1 split in two halves (rows 0-1023 / 1024-2047) for profiling visibility
  gemm_bt<<<dim3(8, 79), 256, 0, stream>>>(Qb, Mt, C1t, b3d, 10000, 3200, tinfo, order, 50,
                                           512, 10000LL, 10000, invperm, 0);
  gemm_bt<<<dim3(8, 79), 256, 0, stream>>>(Qb, Mt, C1t, b3d, 10000, 3200, tinfo, order, 50,
                                           512, 10000LL, 10000, invperm, 8);
  // G2: 1x1 conv 512->128
  gemm_bt<<<dim3(1, 313), 256, 0, stream>>>(w2a_bf, C1t, x2t, b2a, 40000, 512, nullptr,
                                            nullptr, 8, 128, 40000LL, 40000, nullptr, 0);
  // G3/G4: 3x3 convs 128->128
  conv3x3_gemm<<<dim3(313), 256, 0, stream>>>(w2b_pk, x2t, x3t, b2b, zp);
  conv3x3_gemm<<<dim3(313), 256, 0, stream>>>(w2c_pk, x3t, x4t, b2c, zp);
  // head
  head_conf<<<157, 256, 0, stream>>>(x4t, w2d, b2d, out);
}

// Round 12
// 282.749 us; speedup vs baseline: 1.4379x; 1.2257x over previous
//
#include <hip/hip_runtime.h>
#include <cstdint>
#include <cstddef>
#include <math.h>

typedef unsigned short u16;
typedef short bf16x8 __attribute__((ext_vector_type(8)));
typedef float f32x4 __attribute__((ext_vector_type(4)));

// ---------- helpers ----------
__device__ __forceinline__ u16 f2bf(float f) {
  union { float f; uint32_t u; } c; c.f = f;
  uint32_t u = c.u;
  return (u16)((u + 0x7FFFu + ((u >> 16) & 1u)) >> 16);
}
__device__ __forceinline__ float bf2f(u16 h) {
  union { uint32_t u; float f; } c; c.u = ((uint32_t)h) << 16;
  return c.f;
}
__device__ __forceinline__ float sigmoidf_(float x) { return 1.f / (1.f + expf(-x)); }

__device__ __forceinline__ void glds16(const void* g, void* l) {
  __builtin_amdgcn_global_load_lds((const __attribute__((address_space(1))) void*)g,
                                   (__attribute__((address_space(3))) void*)l, 16, 0, 0);
}

// column permutation: valid (s<=e) pairs compacted in natural order, invalid at end
__device__ __forceinline__ int col_rank(int p) {
  int s = p / 100, e = p - s * 100;
  int tri = (s * (s - 1)) >> 1;
  return (e >= s) ? (p - tri - s) : (5050 + tri + e);
}

// ---------- front-end 1D convs, ILP version: 4 t per thread via float4 ----------
__global__ void conv1d_k3v(const float* __restrict__ in, const float* __restrict__ w,
                           const float* __restrict__ bias, float* __restrict__ out,
                           int Cin_total, int Cin_g, int ocPerGroup, int OC) {
  int idx = blockIdx.x * 256 + threadIdx.x;
  int sub = idx % 25;
  int tmp = idx / 25;
  int oc = tmp % OC;
  int bb = tmp / OC;
  if (bb >= 4) return;
  int t4 = sub * 4;
  int g = oc / ocPerGroup;
  const float* ip = in + ((size_t)bb * Cin_total + (size_t)g * Cin_g) * 100 + t4;
  const float* wp = w + (size_t)oc * Cin_g * 3;
  float bs = bias[oc];
  float s0 = bs, s1 = bs, s2 = bs, s3 = bs;
  #pragma unroll 4
  for (int ic = 0; ic < Cin_g; ++ic) {
    const float* r = ip + (size_t)ic * 100;
    float4 a = *(const float4*)r;
    float xm = (t4 > 0) ? r[-1] : 0.f;
    float xp = (t4 < 96) ? r[4] : 0.f;
    float w0 = wp[ic * 3 + 0], w1 = wp[ic * 3 + 1], w2 = wp[ic * 3 + 2];
    s0 += w0 * xm + w1 * a.x + w2 * a.y;
    s1 += w0 * a.x + w1 * a.y + w2 * a.z;
    s2 += w0 * a.y + w1 * a.z + w2 * a.w;
    s3 += w0 * a.z + w1 * a.w + w2 * xp;
  }
  float4 o;
  o.x = fmaxf(s0, 0.f); o.y = fmaxf(s1, 0.f);
  o.z = fmaxf(s2, 0.f); o.w = fmaxf(s3, 0.f);
  *(float4*)(out + ((size_t)bb * OC + oc) * 100 + t4) = o;
}

// fused s1/e1/p branches (all read `base`), ILP version
__global__ void conv1d_branch_v(const float* __restrict__ in, const float* __restrict__ wS,
                                const float* __restrict__ bS, const float* __restrict__ wE,
                                const float* __restrict__ bE, const float* __restrict__ wP,
                                const float* __restrict__ bP, float* __restrict__ outS,
                                float* __restrict__ outE, u16* __restrict__ Pt) {
  int idx = blockIdx.x * 256 + threadIdx.x;
  int sub = idx % 25;
  int tmp = idx / 25;
  int ocx = tmp % 640;
  int bb = tmp / 640;
  if (bb >= 4) return;
  int t4 = sub * 4;
  const float* w;
  const float* bias;
  const float* ip;
  int Cin_g, oc;
  if (ocx < 512) {
    int sel = ocx >> 8;
    oc = ocx & 255;
    w = sel ? wE : wS;
    bias = sel ? bE : bS;
    int g = oc >> 6;
    ip = in + ((size_t)bb * 256 + (size_t)g * 64) * 100 + t4;
    Cin_g = 64;
  } else {
    oc = ocx - 512;
    w = wP;
    bias = bP;
    ip = in + (size_t)bb * 256 * 100 + t4;
    Cin_g = 256;
  }
  const float* wp = w + (size_t)oc * Cin_g * 3;
  float bs = bias[oc];
  float s0 = bs, s1 = bs, s2 = bs, s3 = bs;
  #pragma unroll 4
  for (int ic = 0; ic < Cin_g; ++ic) {
    const float* r = ip + (size_t)ic * 100;
    float4 a = *(const float4*)r;
    float xm = (t4 > 0) ? r[-1] : 0.f;
    float xp = (t4 < 96) ? r[4] : 0.f;
    float w0 = wp[ic * 3 + 0], w1 = wp[ic * 3 + 1], w2 = wp[ic * 3 + 2];
    s0 += w0 * xm + w1 * a.x + w2 * a.y;
    s1 += w0 * a.x + w1 * a.y + w2 * a.z;
    s2 += w0 * a.y + w1 * a.z + w2 * a.w;
    s3 += w0 * a.z + w1 * a.w + w2 * xp;
  }
  if (ocx < 512) {
    float* out = (ocx < 256) ? outS : outE;
    float4 o;
    o.x = fmaxf(s0, 0.f); o.y = fmaxf(s1, 0.f);
    o.z = fmaxf(s2, 0.f); o.w = fmaxf(s3, 0.f);
    *(float4*)(out + ((size_t)bb * 256 + oc) * 100 + t4) = o;
  } else {
    Pt[((size_t)bb * 100 + t4 + 0) * 128 + oc] = f2bf(fmaxf(s0, 0.f));
    Pt[((size_t)bb * 100 + t4 + 1) * 128 + oc] = f2bf(fmaxf(s1, 0.f));
    Pt[((size_t)bb * 100 + t4 + 2) * 128 + oc] = f2bf(fmaxf(s2, 0.f));
    Pt[((size_t)bb * 100 + t4 + 3) * 128 + oc] = f2bf(fmaxf(s3, 0.f));
  }
}

// ---------- fused prep: castw + cast_wq + invperm + tileinfo + zero-page + mask_fill ----------
__global__ void prep_fused(const float* __restrict__ w2a, const float* __restrict__ w2b,
                           const float* __restrict__ w2c, u16* __restrict__ w2a_bf,
                           u16* __restrict__ w2b_pk, u16* __restrict__ w2c_pk,
                           const float* __restrict__ w3d, u16* __restrict__ Wq,
                           int* __restrict__ invperm, int* __restrict__ tinfo,
                           int* __restrict__ order, u16* __restrict__ zp,
                           u16* __restrict__ Mt) {
  int bid = blockIdx.x, tid = threadIdx.x;
  if (bid < 576) {
    int i = bid * 256 + tid;
    if (i < 65536) w2a_bf[i] = f2bf(w2a[i]);
    if (i < 147456) {
      int oc = i / 1152, r = i % 1152, kk = r >> 7, ic = r & 127;
      int src = (oc * 128 + ic) * 9 + kk;
      w2b_pk[i] = f2bf(w2b[src]);
      w2c_pk[i] = f2bf(w2c[src]);
    }
  } else if (bid < 640) {
    int u = (bid - 576) * 256 + tid;  // 16384 threads
    int o = u >> 5, n = u & 31;
    const float* src = w3d + (size_t)o * 4096 + n;
    u16* dst = Wq + (size_t)u * 128;
    for (int c0 = 0; c0 < 128; c0 += 8) {
      __align__(16) u16 h[8];
      #pragma unroll
      for (int j = 0; j < 8; ++j) h[j] = f2bf(src[(size_t)(c0 + j) * 32]);
      *(uint4*)(dst + c0) = *(const uint4*)h;
    }
  } else if (bid < 680) {
    int p = (bid - 640) * 256 + tid;
    if (p < 10000) invperm[col_rank(p)] = p;
  } else if (bid == 680) {
    if (tid < 128) zp[tid] = 0;
    __shared__ int C[128];
    int t = tid;
    int kbmin = 0, cnt = 0;
    if (t < 79) {
      int rlo = t * 128;
      int rhi = rlo + 128;
      if (rhi > 5050) rhi = 5050;
      if (rlo < 5050) {
        int s = 0;
        while (100 * (s + 1) - ((s + 1) * s) / 2 <= rlo) ++s;
        int cum = 100 * s - (s * (s - 1)) / 2;
        int tmin = 100, tmax = -1;
        for (int r = rlo; r < rhi; ++r) {
          while (r - cum >= 100 - s) { ++s; cum = 100 * s - (s * (s - 1)) / 2; }
          int e = s + (r - cum);
          float L = (float)(e - s + 2);
          float sp2 = (float)s - 0.5f * L;
          float ep2 = (float)(e + 1) + 0.5f * L;
          int a = (int)floorf(sp2) - 1;
          if (a < 0) a = 0;
          int b = (int)floorf(ep2) + 2;
          if (b > 99) b = 99;
          if (a < tmin) tmin = a;
          if (b > tmax) tmax = b;
        }
        kbmin = tmin >> 1;
        cnt = (tmax >> 1) - kbmin + 1;
      }
      tinfo[2 * t] = kbmin;
      tinfo[2 * t + 1] = cnt;
    }
    if (t < 128) C[t] = (t < 79) ? cnt : -1;
    __syncthreads();
    if (t < 79) {
      int pos = 0;
      int ct = C[t];
      for (int u = 0; u < 79; ++u) {
        int cu = C[u];
        pos += (cu > ct) || (cu == ct && u < t);
      }
      order[pos] = t;
    }
  } else {
    // mask_fill: analytic float64 replica of the Python reference, p-indexed
    int u = (bid - 681) * 256 + tid;   // over 10000*32 = 320000
    if (u >= 320000) return;
    int p = u >> 5, n = u & 31;
    int s = p / 100, e = p - s * 100;
    if (e < s) return;                 // invalid pair -> zero column (already memset)
    int r = p - ((s * (s - 1)) >> 1) - s;   // col_rank for valid p
    double sp = (double)s, ep = (double)(e + 1);
    double L = ep - sp + 1.0;
    double sp2 = sp - L * 0.5;
    double ep2 = ep + L * 0.5;
    double step = (ep2 - sp2) / 95.0;
    double win[8];
    #pragma unroll
    for (int k = 0; k < 8; ++k) win[k] = 0.0;
    int base = -1;
    #pragma unroll
    for (int jj = 0; jj < 3; ++jj) {
      double pos = sp2 + step * (double)(n * 3 + jj);
      double ip;
      double fr = modf(pos, &ip);
      int it = (int)ip;
      if (it >= 0 && it < 99) {
        if (base < 0) base = it;
        int off = it - base;
        win[off] += (1.0 - fr) / 3.0;
        win[off + 1] += fr / 3.0;
      }
    }
    if (base >= 0) {
      u16* dst = Mt + (size_t)r * 3200 + n;
      #pragma unroll
      for (int k = 0; k < 8; ++k) {
        int t = base + k;
        if (t < 100) dst[(size_t)t * 32] = f2bf((float)win[k]);
      }
    }
  }
}

// ---------- shared MFMA pieces (T2 XOR-swizzled reads; sources pre-swizzled) ----------
template<int MI>
__device__ __forceinline__ void mfma_stepT(const u16* As, const u16* Bs, int l, int wm, int wn,
                                           f32x4 (&acc)[MI][4]) {
  int m15 = l & 15, q = l >> 4, sw = m15 & 7;
  #pragma unroll
  for (int kk = 0; kk < 2; ++kk) {
    int koff = ((kk * 4 + q) ^ sw) * 8;
    bf16x8 av[MI], bv[4];
    #pragma unroll
    for (int i = 0; i < MI; ++i)
      av[i] = *(const bf16x8*)(As + (size_t)(wm * (MI * 16) + i * 16 + m15) * 64 + koff);
    #pragma unroll
    for (int j = 0; j < 4; ++j)
      bv[j] = *(const bf16x8*)(Bs + (size_t)(wn * 64 + j * 16 + m15) * 64 + koff);
    #pragma unroll
    for (int i = 0; i < MI; ++i) {
      #pragma unroll
      for (int j = 0; j < 4; ++j)
        acc[i][j] = __builtin_amdgcn_mfma_f32_16x16x32_bf16(av[i], bv[j], acc[i][j], 0, 0, 0);
    }
  }
}

template<int MI>
__device__ __forceinline__ void epilogue_storeT(f32x4 (&acc)[MI][4], u16* OUT,
                                                const float* bias, int row0, int col0, int l,
                                                int wm, int wn, int N, int OC, long long NPB,
                                                const int* colmap) {
  int r4 = (l >> 4) * 4, c1 = l & 15;
  int cols[4], pcols[4];
  #pragma unroll
  for (int j = 0; j < 4; ++j) {
    cols[j] = col0 + wn * 64 + j * 16 + c1;
    pcols[j] = (cols[j] < N) ? (colmap ? colmap[cols[j]] : cols[j]) : 0;
  }
  #pragma unroll
  for (int i = 0; i < MI; ++i) {
    int row = row0 + wm * (MI * 16) + i * 16 + r4;
    int ob = row % OC;
    size_t obb = (size_t)(row / OC) * (size_t)OC * (size_t)NPB;
    float b0 = bias[ob + 0], b1 = bias[ob + 1], b2 = bias[ob + 2], b3 = bias[ob + 3];
    #pragma unroll
    for (int j = 0; j < 4; ++j) {
      if (cols[j] < N) {
        f32x4 v = acc[i][j];
        __align__(8) u16 h[4];
        h[0] = f2bf(fmaxf(v[0] + b0, 0.f));
        h[1] = f2bf(fmaxf(v[1] + b1, 0.f));
        h[2] = f2bf(fmaxf(v[2] + b2, 0.f));
        h[3] = f2bf(fmaxf(v[3] + b3, 0.f));
        *(uint2*)(OUT + obb + (size_t)pcols[j] * OC + ob) = *(const uint2*)h;
      }
    }
  }
}

// ---------- generic BT-GEMM; single-buffer 2-barrier loop (m97 structure) ----------
__global__ __launch_bounds__(256, 2) void gemm_bt(const u16* __restrict__ A,
                                                  const u16* __restrict__ B,
                                                  u16* __restrict__ OUT,
                                                  const float* __restrict__ bias, int N, int K,
                                                  const int* __restrict__ tinfo,
                                                  const int* __restrict__ order, int kblocks,
                                                  int OC, long long NPB, int NclampB,
                                                  const int* __restrict__ colmap) {
  __shared__ __align__(16) u16 As[128 * 64];
  __shared__ __align__(16) u16 Bs[128 * 64];
  int mt = blockIdx.x;
  int nt = order ? order[blockIdx.y] : blockIdx.y;
  int col0 = nt * 128, row0 = mt * 128;
  int tid = threadIdx.x, w = tid >> 6, l = tid & 63;
  int wm = w >> 1, wn = w & 1;
  int lr = l >> 3;
  int lk_sw = ((l & 7) ^ lr) * 8;
  f32x4 acc[4][4] = {};
  size_t aoff[4];
  size_t boff[4];
  #pragma unroll
  for (int r = 0; r < 4; ++r) {
    int chunk = r * 4 + w;
    int rowA = row0 + chunk * 8 + lr;
    aoff[r] = (size_t)rowA * K + lk_sw;
    int colB = col0 + chunk * 8 + lr;
    if (colB >= NclampB) colB = NclampB - 1;
    boff[r] = (size_t)colB * K + lk_sw;
  }
  int kbmin = 0, cnt = kblocks;
  if (tinfo) { kbmin = tinfo[2 * nt]; cnt = tinfo[2 * nt + 1]; }
  for (int i = 0; i < cnt; ++i) {
    int k0 = (kbmin + i) * 64;
    #pragma unroll
    for (int r = 0; r < 4; ++r) {
      int chunk = r * 4 + w;
      glds16(A + aoff[r] + k0, As + chunk * 512);
      glds16(B + boff[r] + k0, Bs + chunk * 512);
    }
    __syncthreads();
    mfma_stepT<4>(As, Bs, l, wm, wn, acc);
    __syncthreads();
  }
  epilogue_storeT<4>(acc, OUT, bias, row0, col0, l, wm, wn, N, OC, NPB, colmap);
}

// ---------- qprep as MFMA GEMM + fused start/end sigmoid heads ----------
// blockIdx.x < 128: GEMM Qb[(b*512+o)][t*32+n]; blockIdx.x == 128: sigmoid heads
// NOTE: e1buf/s1buf must NOT alias Qb (GEMM blocks run concurrently with sigmoid blocks)
__global__ __launch_bounds__(256, 2) void qprep_sig(const u16* __restrict__ Wq,
                                                    const u16* __restrict__ Pt,
                                                    u16* __restrict__ Qb,
                                                    const float* __restrict__ s1,
                                                    const float* __restrict__ e1,
                                                    const float* __restrict__ ws2,
                                                    const float* __restrict__ bs2,
                                                    const float* __restrict__ we2,
                                                    const float* __restrict__ be2,
                                                    float* __restrict__ out) {
  if (blockIdx.x == 128) {
    int t = threadIdx.x & 127;
    int sel = threadIdx.x >> 7;
    int bb = blockIdx.y;
    if (t >= 100) return;
    const float* in = sel ? e1 : s1;
    const float* w = sel ? we2 : ws2;
    float s = sel ? be2[0] : bs2[0];
    #pragma unroll 8
    for (int c = 0; c < 256; ++c) s += w[c] * in[((size_t)bb * 256 + c) * 100 + t];
    out[80000 + sel * 400 + bb * 100 + t] = sigmoidf_(s);
    return;
  }
  __shared__ __align__(16) u16 As[128 * 64];
  __shared__ __align__(16) u16 Bs[128 * 64];
  int mt = blockIdx.x, nt = blockIdx.y;
  int col0 = nt * 128, row0 = mt * 128;
  int tid = threadIdx.x, w = tid >> 6, l = tid & 63;
  int wm = w >> 1, wn = w & 1;
  int lr = l >> 3;
  int lk_sw = ((l & 7) ^ lr) * 8;
  f32x4 acc[4][4] = {};
  size_t aoff[4];
  size_t boff[4];
  #pragma unroll
  for (int r = 0; r < 4; ++r) {
    int chunk = r * 4 + w;
    int rowA = row0 + chunk * 8 + lr;
    aoff[r] = (size_t)rowA * 128 + lk_sw;
    int colB = col0 + chunk * 8 + lr;
    if (colB >= 400) colB = 399;
    boff[r] = (size_t)colB * 128 + lk_sw;
  }
  #pragma unroll
  for (int kb = 0; kb < 2; ++kb) {
    int k0 = kb * 64;
    #pragma unroll
    for (int r = 0; r < 4; ++r) {
      int chunk = r * 4 + w;
      glds16(Wq + aoff[r] + k0, As + chunk * 512);
      glds16(Pt + boff[r] + k0, Bs + chunk * 512);
    }
    __syncthreads();
    mfma_stepT<4>(As, Bs, l, wm, wn, acc);
    __syncthreads();
  }
  int r4 = (l >> 4) * 4, c1 = l & 15;
  #pragma unroll
  for (int i = 0; i < 4; ++i) {
    int row = row0 + wm * 64 + i * 16 + r4;
    int o = row >> 5, n = row & 31;
    #pragma unroll
    for (int j = 0; j < 4; ++j) {
      int col = col0 + wn * 64 + j * 16 + c1;
      if (col < 400) {
        int b = col / 100, t = col - b * 100;
        f32x4 v = acc[i][j];
        __align__(8) u16 h[4];
        h[0] = f2bf(v[0]);
        h[1] = f2bf(v[1]);
        h[2] = f2bf(v[2]);
        h[3] = f2bf(v[3]);
        *(uint2*)(Qb + ((size_t)(b * 512 + o)) * 3200 + t * 32 + n) = *(const uint2*)h;
      }
    }
  }
}

// ---------- 3x3 conv as shifted BT-GEMM ----------
__global__ __launch_bounds__(256, 2) void conv3x3_gemm(const u16* __restrict__ Apk,
                                                       const u16* __restrict__ X,
                                                       u16* __restrict__ OUT,
                                                       const float* __restrict__ bias,
                                                       const u16* __restrict__ zp) {
  __shared__ __align__(16) u16 As[128 * 64];
  __shared__ __align__(16) u16 Bs[128 * 64];
  int nt = blockIdx.x;
  int col0 = nt * 128;
  int tid = threadIdx.x, w = tid >> 6, l = tid & 63;
  int wm = w >> 1, wn = w & 1;
  int lr = l >> 3;
  int lk_sw = ((l & 7) ^ lr) * 8;
  int cj[4], yy[4], xx[4];
  bool vv[4];
  size_t aoff[4];
  #pragma unroll
  for (int r = 0; r < 4; ++r) {
    int chunk = r * 4 + w;
    int c = col0 + chunk * 8 + lr;
    cj[r] = c;
    vv[r] = (c < 40000);
    int p = c % 10000;
    yy[r] = p / 100;
    xx[r] = p % 100;
    aoff[r] = (size_t)(chunk * 8 + lr) * 1152 + lk_sw;
  }
  f32x4 acc[4][4] = {};
  for (int s = 0; s < 9; ++s) {
    int dy = s / 3 - 1, dx = s % 3 - 1;
    int doff = dy * 100 + dx;
    #pragma unroll
    for (int half = 0; half < 2; ++half) {
      int k0 = s * 128 + half * 64;
      int c0 = half * 64;
      #pragma unroll
      for (int r = 0; r < 4; ++r) {
        int chunk = r * 4 + w;
        glds16(Apk + aoff[r] + k0, As + chunk * 512);
        int y2 = yy[r] + dy, x2 = xx[r] + dx;
        bool ok = vv[r] && ((unsigned)y2 < 100u) && ((unsigned)x2 < 100u);
        const u16* src = ok ? (X + (size_t)(cj[r] + doff) * 128 + c0 + lk_sw) : zp;
        glds16(src, Bs + chunk * 512);
      }
      __syncthreads();
      mfma_stepT<4>(As, Bs, l, wm, wn, acc);
      __syncthreads();
    }
  }
  epilogue_storeT<4>(acc, OUT, bias, 0, col0, l, wm, wn, 40000, 128, 40000LL, nullptr);
}

// ---------- final head ----------
__global__ void head_conf(const u16* __restrict__ x4t, const float* __restrict__ w2d,
                          const float* __restrict__ b2d, float* __restrict__ out) {
  __shared__ float wS[256];
  int tid = threadIdx.x;
  wS[tid] = w2d[tid];
  __syncthreads();
  int u = blockIdx.x * 256 + tid;
  if (u >= 40000) return;
  int b = u / 10000, pidx = u % 10000;
  const uint4* xr = (const uint4*)(x4t + (size_t)u * 128);
  float s0 = b2d[0], s1 = b2d[1];
  #pragma unroll 4
  for (int v = 0; v < 16; ++v) {
    uint4 q = xr[v];
    int c = v * 8;
    uint32_t d;
    float lo, hi;
    d = q.x; lo = __uint_as_float(d << 16); hi = __uint_as_float(d & 0xffff0000u);
    s0 += wS[c] * lo + wS[c + 1] * hi; s1 += wS[128 + c] * lo + wS[129 + c] * hi;
    d = q.y; lo = __uint_as_float(d << 16); hi = __uint_as_float(d & 0xffff0000u);
    s0 += wS[c + 2] * lo + wS[c + 3] * hi; s1 += wS[130 + c] * lo + wS[131 + c] * hi;
    d = q.z; lo = __uint_as_float(d << 16); hi = __uint_as_float(d & 0xffff0000u);
    s0 += wS[c + 4] * lo + wS[c + 5] * hi; s1 += wS[132 + c] * lo + wS[133 + c] * hi;
    d = q.w; lo = __uint_as_float(d << 16); hi = __uint_as_float(d & 0xffff0000u);
    s0 += wS[c + 6] * lo + wS[c + 7] * hi; s1 += wS[134 + c] * lo + wS[135 + c] * hi;
  }
  out[((size_t)b * 2 + 0) * 10000 + pidx] = sigmoidf_(s0);
  out[((size_t)b * 2 + 1) * 10000 + pidx] = sigmoidf_(s1);
}

// ---------- launch ----------
extern "C" void kernel_launch(void* const* d_in, const int* in_sizes, int n_in, void* d_out,
                              int out_size, void* d_ws, size_t ws_size, hipStream_t stream) {
  const float* inputs = (const float*)d_in[0];
  const float* w_b1 = (const float*)d_in[1];
  const float* b_b1 = (const float*)d_in[2];
  const float* w_b2 = (const float*)d_in[3];
  const float* b_b2 = (const float*)d_in[4];
  const float* w_s1 = (const float*)d_in[5];
  const float* b_s1 = (const float*)d_in[6];
  const float* w_s2 = (const float*)d_in[7];
  const float* b_s2 = (const float*)d_in[8];
  const float* w_e1 = (const float*)d_in[9];
  const float* b_e1 = (const float*)d_in[10];
  const float* w_e2 = (const float*)d_in[11];
  const float* b_e2 = (const float*)d_in[12];
  const float* w_p1 = (const float*)d_in[13];
  const float* b_p1 = (const float*)d_in[14];
  const float* w3d = (const float*)d_in[15];
  const float* b3d = (const float*)d_in[16];
  const float* w2a = (const float*)d_in[17];
  const float* b2a = (const float*)d_in[18];
  const float* w2b = (const float*)d_in[19];
  const float* b2b = (const float*)d_in[20];
  const float* w2c = (const float*)d_in[21];
  const float* b2c = (const float*)d_in[22];
  const float* w2d = (const float*)d_in[23];
  const float* b2d = (const float*)d_in[24];
  float* out = (float*)d_out;
  char* ws = (char*)d_ws;

  int* tinfo = (int*)(ws + 0);
  int* order = (int*)(ws + 2048);
  u16* zp = (u16*)(ws + 16384);
  int* invperm = (int*)(ws + 45056);
  float* base1 = (float*)(ws + 90112);          // 409600
  float* base = (float*)(ws + 499712);          // 409600
  float* s1buf = (float*)(ws + 909312);         // 409600
  u16* Pt = (u16*)(ws + 1318912);               // 102400
  u16* w2a_bf = (u16*)(ws + 1421312);           // 131072
  u16* w2b_pk = (u16*)(ws + 1552384);           // 294912
  u16* w2c_pk = (u16*)(ws + 1847296);           // 294912
  u16* Qb = (u16*)(ws + 2142208);               // 13107200 (ends 15249408)
  u16* Mt = (u16*)(ws + 15249408);              // rows 0..5119 used -> ends 48017408
  float* e1buf = (float*)(ws + 48017408);       // 409600, in Mt-region free tail (no alias!)
  u16* C1t = (u16*)(ws + 79249408);             // 40960000  (end 120209408)
  u16* Wq = (u16*)(ws + 79249408);              // aliases C1t: dead before G1 writes C1t
  u16* x2t = Qb;   // alias: Qb dead after G1
  u16* x3t = C1t;  // alias: C1t dead after G2
  u16* x4t = Mt;   // alias: Mt dead after G1 (x4t ends 25489408, clear of e1buf)

  // 1) zero Mt valid region (prep's mask_fill blocks write into it next)
  hipMemsetAsync(Mt, 0, (size_t)5120 * 3200 * 2, stream);

  // 2) fused prep: weights cast/repack, invperm, tile spans + order, zero page, mask fill
  prep_fused<<<1931, 256, 0, stream>>>(w2a, w2b, w2c, w2a_bf, w2b_pk, w2c_pk, w3d, Wq,
                                       invperm, tinfo, order, zp, Mt);

  // 3-5) front end (fp32 exact, ILP-vectorized)
  conv1d_k3v<<<100, 256, 0, stream>>>(inputs, w_b1, b_b1, base1, 400, 100, 64, 256);
  conv1d_k3v<<<100, 256, 0, stream>>>(base1, w_b2, b_b2, base, 256, 64, 64, 256);
  conv1d_branch_v<<<250, 256, 0, stream>>>(base, w_s1, b_s1, w_e1, b_e1, w_p1, b_p1,
                                           s1buf, e1buf, Pt);

  // 6) qprep GEMM [16384 x 400 x 128] + fused start/end sigmoid heads
  qprep_sig<<<dim3(129, 4), 256, 0, stream>>>(Wq, Pt, Qb, s1buf, e1buf, w_s2, b_s2,
                                              w_e2, b_e2, out);

  // 7) G1: out3d, 128x128 tiles, longest-first; de-permuted store into C1t[(b,p)][o]
  gemm_bt<<<dim3(16, 79), 256, 0, stream>>>(Qb, Mt, C1t, b3d, 10000, 3200, tinfo, order, 50,
                                            512, 10000LL, 10000, invperm);
  // 8) G2: 1x1 conv 512->128
  gemm_bt<<<dim3(1, 313), 256, 0, stream>>>(w2a_bf, C1t, x2t, b2a, 40000, 512, nullptr,
                                            nullptr, 8, 128, 40000LL, 40000, nullptr);
  // 9-10) 3x3 convs 128->128
  conv3x3_gemm<<<dim3(313), 256, 0, stream>>>(w2b_pk, x2t, x3t, b2b, zp);
  conv3x3_gemm<<<dim3(313), 256, 0, stream>>>(w2c_pk, x3t, x4t, b2c, zp);
  // 11) head
  head_conf<<<157, 256, 0, stream>>>(x4t, w2d, b2d, out);
}

// Round 13
// 257.389 us; speedup vs baseline: 1.5796x; 1.0985x over previous
//
#include <hip/hip_runtime.h>
#include <cstdint>
#include <cstddef>
#include <math.h>

typedef unsigned short u16;
typedef short bf16x8 __attribute__((ext_vector_type(8)));
typedef float f32x4 __attribute__((ext_vector_type(4)));

// ---------- helpers ----------
__device__ __forceinline__ u16 f2bf(float f) {
  union { float f; uint32_t u; } c; c.f = f;
  uint32_t u = c.u;
  return (u16)((u + 0x7FFFu + ((u >> 16) & 1u)) >> 16);
}
__device__ __forceinline__ float bf2f(u16 h) {
  union { uint32_t u; float f; } c; c.u = ((uint32_t)h) << 16;
  return c.f;
}
__device__ __forceinline__ float sigmoidf_(float x) { return 1.f / (1.f + expf(-x)); }

__device__ __forceinline__ void glds16(const void* g, void* l) {
  __builtin_amdgcn_global_load_lds((const __attribute__((address_space(1))) void*)g,
                                   (__attribute__((address_space(3))) void*)l, 16, 0, 0);
}

// column permutation: valid (s<=e) pairs compacted in natural order, invalid at end
__device__ __forceinline__ int col_rank(int p) {
  int s = p / 100, e = p - s * 100;
  int tri = (s * (s - 1)) >> 1;
  return (e >= s) ? (p - tri - s) : (5050 + tri + e);
}

// ---------- front-end 1D convs, ILP version: 4 t per thread via float4 ----------
__global__ void conv1d_k3v(const float* __restrict__ in, const float* __restrict__ w,
                           const float* __restrict__ bias, float* __restrict__ out,
                           int Cin_total, int Cin_g, int ocPerGroup, int OC) {
  int idx = blockIdx.x * 256 + threadIdx.x;
  int sub = idx % 25;
  int tmp = idx / 25;
  int oc = tmp % OC;
  int bb = tmp / OC;
  if (bb >= 4) return;
  int t4 = sub * 4;
  int g = oc / ocPerGroup;
  const float* ip = in + ((size_t)bb * Cin_total + (size_t)g * Cin_g) * 100 + t4;
  const float* wp = w + (size_t)oc * Cin_g * 3;
  float bs = bias[oc];
  float s0 = bs, s1 = bs, s2 = bs, s3 = bs;
  #pragma unroll 4
  for (int ic = 0; ic < Cin_g; ++ic) {
    const float* r = ip + (size_t)ic * 100;
    float4 a = *(const float4*)r;
    float xm = (t4 > 0) ? r[-1] : 0.f;
    float xp = (t4 < 96) ? r[4] : 0.f;
    float w0 = wp[ic * 3 + 0], w1 = wp[ic * 3 + 1], w2 = wp[ic * 3 + 2];
    s0 += w0 * xm + w1 * a.x + w2 * a.y;
    s1 += w0 * a.x + w1 * a.y + w2 * a.z;
    s2 += w0 * a.y + w1 * a.z + w2 * a.w;
    s3 += w0 * a.z + w1 * a.w + w2 * xp;
  }
  float4 o;
  o.x = fmaxf(s0, 0.f); o.y = fmaxf(s1, 0.f);
  o.z = fmaxf(s2, 0.f); o.w = fmaxf(s3, 0.f);
  *(float4*)(out + ((size_t)bb * OC + oc) * 100 + t4) = o;
}

// fused s1/e1/p branches (all read `base`), ILP version
__global__ void conv1d_branch_v(const float* __restrict__ in, const float* __restrict__ wS,
                                const float* __restrict__ bS, const float* __restrict__ wE,
                                const float* __restrict__ bE, const float* __restrict__ wP,
                                const float* __restrict__ bP, float* __restrict__ outS,
                                float* __restrict__ outE, u16* __restrict__ Pt) {
  int idx = blockIdx.x * 256 + threadIdx.x;
  int sub = idx % 25;
  int tmp = idx / 25;
  int ocx = tmp % 640;
  int bb = tmp / 640;
  if (bb >= 4) return;
  int t4 = sub * 4;
  const float* w;
  const float* bias;
  const float* ip;
  int Cin_g, oc;
  if (ocx < 512) {
    int sel = ocx >> 8;
    oc = ocx & 255;
    w = sel ? wE : wS;
    bias = sel ? bE : bS;
    int g = oc >> 6;
    ip = in + ((size_t)bb * 256 + (size_t)g * 64) * 100 + t4;
    Cin_g = 64;
  } else {
    oc = ocx - 512;
    w = wP;
    bias = bP;
    ip = in + (size_t)bb * 256 * 100 + t4;
    Cin_g = 256;
  }
  const float* wp = w + (size_t)oc * Cin_g * 3;
  float bs = bias[oc];
  float s0 = bs, s1 = bs, s2 = bs, s3 = bs;
  #pragma unroll 4
  for (int ic = 0; ic < Cin_g; ++ic) {
    const float* r = ip + (size_t)ic * 100;
    float4 a = *(const float4*)r;
    float xm = (t4 > 0) ? r[-1] : 0.f;
    float xp = (t4 < 96) ? r[4] : 0.f;
    float w0 = wp[ic * 3 + 0], w1 = wp[ic * 3 + 1], w2 = wp[ic * 3 + 2];
    s0 += w0 * xm + w1 * a.x + w2 * a.y;
    s1 += w0 * a.x + w1 * a.y + w2 * a.z;
    s2 += w0 * a.y + w1 * a.z + w2 * a.w;
    s3 += w0 * a.z + w1 * a.w + w2 * xp;
  }
  if (ocx < 512) {
    float* out = (ocx < 256) ? outS : outE;
    float4 o;
    o.x = fmaxf(s0, 0.f); o.y = fmaxf(s1, 0.f);
    o.z = fmaxf(s2, 0.f); o.w = fmaxf(s3, 0.f);
    *(float4*)(out + ((size_t)bb * 256 + oc) * 100 + t4) = o;
  } else {
    Pt[((size_t)bb * 100 + t4 + 0) * 128 + oc] = f2bf(fmaxf(s0, 0.f));
    Pt[((size_t)bb * 100 + t4 + 1) * 128 + oc] = f2bf(fmaxf(s1, 0.f));
    Pt[((size_t)bb * 100 + t4 + 2) * 128 + oc] = f2bf(fmaxf(s2, 0.f));
    Pt[((size_t)bb * 100 + t4 + 3) * 128 + oc] = f2bf(fmaxf(s3, 0.f));
  }
}

// ---------- fused prep: castw + cast_wq + invperm + tileinfo + zp + mask rows + conv1 ----------
// Mask rows built in LDS (zeroed, scattered, then written coalesced) -> no global memset needed.
__global__ void prep_fused(const float* __restrict__ w2a, const float* __restrict__ w2b,
                           const float* __restrict__ w2c, u16* __restrict__ w2a_bf,
                           u16* __restrict__ w2b_pk, u16* __restrict__ w2c_pk,
                           const float* __restrict__ w3d, u16* __restrict__ Wq,
                           int* __restrict__ invperm, int* __restrict__ tinfo,
                           int* __restrict__ order, u16* __restrict__ zp,
                           u16* __restrict__ Mt, const float* __restrict__ inputs,
                           const float* __restrict__ w_b1, const float* __restrict__ b_b1,
                           float* __restrict__ base1) {
  __shared__ __align__(16) u16 ML[4 * 3200];   // 25.6 KB: 4 mask rows
  __shared__ int C[128];
  int bid = blockIdx.x, tid = threadIdx.x;
  if (bid < 576) {
    int i = bid * 256 + tid;
    if (i < 65536) w2a_bf[i] = f2bf(w2a[i]);
    if (i < 147456) {
      int oc = i / 1152, r = i % 1152, kk = r >> 7, ic = r & 127;
      int src = (oc * 128 + ic) * 9 + kk;
      w2b_pk[i] = f2bf(w2b[src]);
      w2c_pk[i] = f2bf(w2c[src]);
    }
  } else if (bid < 640) {
    int u = (bid - 576) * 256 + tid;  // 16384 threads
    int o = u >> 5, n = u & 31;
    const float* src = w3d + (size_t)o * 4096 + n;
    u16* dst = Wq + (size_t)u * 128;
    for (int c0 = 0; c0 < 128; c0 += 8) {
      __align__(16) u16 h[8];
      #pragma unroll
      for (int j = 0; j < 8; ++j) h[j] = f2bf(src[(size_t)(c0 + j) * 32]);
      *(uint4*)(dst + c0) = *(const uint4*)h;
    }
  } else if (bid < 680) {
    int p = (bid - 640) * 256 + tid;
    if (p < 10000) invperm[col_rank(p)] = p;
  } else if (bid == 680) {
    if (tid < 128) zp[tid] = 0;
    int t = tid;
    int kbmin = 0, cnt = 0;
    if (t < 79) {
      int rlo = t * 128;
      int rhi = rlo + 128;
      if (rhi > 5050) rhi = 5050;
      if (rlo < 5050) {
        int s = 0;
        while (100 * (s + 1) - ((s + 1) * s) / 2 <= rlo) ++s;
        int cum = 100 * s - (s * (s - 1)) / 2;
        int tmin = 100, tmax = -1;
        for (int r = rlo; r < rhi; ++r) {
          while (r - cum >= 100 - s) { ++s; cum = 100 * s - (s * (s - 1)) / 2; }
          int e = s + (r - cum);
          float L = (float)(e - s + 2);
          float sp2 = (float)s - 0.5f * L;
          float ep2 = (float)(e + 1) + 0.5f * L;
          int a = (int)floorf(sp2) - 1;
          if (a < 0) a = 0;
          int b = (int)floorf(ep2) + 2;
          if (b > 99) b = 99;
          if (a < tmin) tmin = a;
          if (b > tmax) tmax = b;
        }
        kbmin = tmin >> 1;
        cnt = (tmax >> 1) - kbmin + 1;
      }
      tinfo[2 * t] = kbmin;
      tinfo[2 * t + 1] = cnt;
    }
    if (t < 128) C[t] = (t < 79) ? cnt : -1;
    __syncthreads();
    if (t < 79) {
      int pos = 0;
      int ct = C[t];
      for (int u = 0; u < 79; ++u) {
        int cu = C[u];
        pos += (cu > ct) || (cu == ct && u < t);
      }
      order[pos] = t;
    }
  } else if (bid < 1961) {
    // mask rows: 4 rows per block, built in LDS then written coalesced
    int r0 = (bid - 681) * 4;                  // 0..5116
    uint32_t* MZ = (uint32_t*)ML;
    for (int i = tid; i < 6400; i += 256) MZ[i] = 0;
    __syncthreads();
    int g = tid >> 6, lane = tid & 63;
    int r = r0 + g;
    if (r < 5050 && lane < 32) {
      int n = lane;
      // invert rank -> (s,e): cum(s) = s*(201-s)/2
      int s = (int)((201.0 - sqrt((double)(40401 - 8 * r))) * 0.5);
      if (s < 0) s = 0;
      while (s * (201 - s) / 2 > r) --s;
      while ((s + 1) * (200 - s) / 2 <= r) ++s;
      int e = s + (r - s * (201 - s) / 2);
      double sp = (double)s, ep = (double)(e + 1);
      double L = ep - sp + 1.0;
      double sp2 = sp - L * 0.5;
      double ep2 = ep + L * 0.5;
      double step = (ep2 - sp2) / 95.0;
      double win[8];
      #pragma unroll
      for (int k = 0; k < 8; ++k) win[k] = 0.0;
      int base = -1;
      #pragma unroll
      for (int jj = 0; jj < 3; ++jj) {
        double pos = sp2 + step * (double)(n * 3 + jj);
        double ip;
        double fr = modf(pos, &ip);
        int it = (int)ip;
        if (it >= 0 && it < 99) {
          if (base < 0) base = it;
          int off = it - base;
          win[off] += (1.0 - fr) / 3.0;
          win[off + 1] += fr / 3.0;
        }
      }
      if (base >= 0) {
        u16* dst = ML + g * 3200 + n;
        #pragma unroll
        for (int k = 0; k < 8; ++k) {
          int t = base + k;
          if (t < 100) dst[t * 32] = f2bf((float)win[k]);
        }
      }
    }
    __syncthreads();
    for (int i = tid; i < 1600; i += 256) {    // 4 rows x 400 uint4
      int rl = i / 400, off = i - rl * 400;
      *(uint4*)(Mt + (size_t)(r0 + rl) * 3200 + off * 8) = ((const uint4*)ML)[i];
    }
  } else {
    // conv1: inputs -> base1 (grouped 4x100->256, k=3, relu), ILP float4 version
    int idx = (bid - 1961) * 256 + tid;        // < 25600
    int sub = idx % 25;
    int tmp = idx / 25;
    int oc = tmp % 256;
    int bb = tmp / 256;
    if (bb >= 4) return;
    int t4 = sub * 4;
    int g = oc >> 6;
    const float* ip = inputs + ((size_t)bb * 400 + (size_t)g * 100) * 100 + t4;
    const float* wp = w_b1 + (size_t)oc * 300;
    float bs = b_b1[oc];
    float s0 = bs, s1 = bs, s2 = bs, s3 = bs;
    #pragma unroll 4
    for (int ic = 0; ic < 100; ++ic) {
      const float* rr = ip + (size_t)ic * 100;
      float4 a = *(const float4*)rr;
      float xm = (t4 > 0) ? rr[-1] : 0.f;
      float xp = (t4 < 96) ? rr[4] : 0.f;
      float w0 = wp[ic * 3 + 0], w1 = wp[ic * 3 + 1], w2 = wp[ic * 3 + 2];
      s0 += w0 * xm + w1 * a.x + w2 * a.y;
      s1 += w0 * a.x + w1 * a.y + w2 * a.z;
      s2 += w0 * a.y + w1 * a.z + w2 * a.w;
      s3 += w0 * a.z + w1 * a.w + w2 * xp;
    }
    float4 o;
    o.x = fmaxf(s0, 0.f); o.y = fmaxf(s1, 0.f);
    o.z = fmaxf(s2, 0.f); o.w = fmaxf(s3, 0.f);
    *(float4*)(base1 + ((size_t)bb * 256 + oc) * 100 + t4) = o;
  }
}

// ---------- shared MFMA pieces (T2 XOR-swizzled reads; sources pre-swizzled) ----------
template<int MI>
__device__ __forceinline__ void mfma_stepT(const u16* As, const u16* Bs, int l, int wm, int wn,
                                           f32x4 (&acc)[MI][4]) {
  int m15 = l & 15, q = l >> 4, sw = m15 & 7;
  #pragma unroll
  for (int kk = 0; kk < 2; ++kk) {
    int koff = ((kk * 4 + q) ^ sw) * 8;
    bf16x8 av[MI], bv[4];
    #pragma unroll
    for (int i = 0; i < MI; ++i)
      av[i] = *(const bf16x8*)(As + (size_t)(wm * (MI * 16) + i * 16 + m15) * 64 + koff);
    #pragma unroll
    for (int j = 0; j < 4; ++j)
      bv[j] = *(const bf16x8*)(Bs + (size_t)(wn * 64 + j * 16 + m15) * 64 + koff);
    #pragma unroll
    for (int i = 0; i < MI; ++i) {
      #pragma unroll
      for (int j = 0; j < 4; ++j)
        acc[i][j] = __builtin_amdgcn_mfma_f32_16x16x32_bf16(av[i], bv[j], acc[i][j], 0, 0, 0);
    }
  }
}

template<int MI>
__device__ __forceinline__ void epilogue_storeT(f32x4 (&acc)[MI][4], u16* OUT,
                                                const float* bias, int row0, int col0, int l,
                                                int wm, int wn, int N, int OC, long long NPB,
                                                const int* colmap) {
  int r4 = (l >> 4) * 4, c1 = l & 15;
  int cols[4], pcols[4];
  #pragma unroll
  for (int j = 0; j < 4; ++j) {
    cols[j] = col0 + wn * 64 + j * 16 + c1;
    pcols[j] = (cols[j] < N) ? (colmap ? colmap[cols[j]] : cols[j]) : 0;
  }
  #pragma unroll
  for (int i = 0; i < MI; ++i) {
    int row = row0 + wm * (MI * 16) + i * 16 + r4;
    int ob = row % OC;
    size_t obb = (size_t)(row / OC) * (size_t)OC * (size_t)NPB;
    float b0 = bias[ob + 0], b1 = bias[ob + 1], b2 = bias[ob + 2], b3 = bias[ob + 3];
    #pragma unroll
    for (int j = 0; j < 4; ++j) {
      if (cols[j] < N) {
        f32x4 v = acc[i][j];
        __align__(8) u16 h[4];
        h[0] = f2bf(fmaxf(v[0] + b0, 0.f));
        h[1] = f2bf(fmaxf(v[1] + b1, 0.f));
        h[2] = f2bf(fmaxf(v[2] + b2, 0.f));
        h[3] = f2bf(fmaxf(v[3] + b3, 0.f));
        *(uint2*)(OUT + obb + (size_t)pcols[j] * OC + ob) = *(const uint2*)h;
      }
    }
  }
}

// ---------- generic BT-GEMM; single-buffer 2-barrier loop (m97 structure) ----------
__global__ __launch_bounds__(256, 2) void gemm_bt(const u16* __restrict__ A,
                                                  const u16* __restrict__ B,
                                                  u16* __restrict__ OUT,
                                                  const float* __restrict__ bias, int N, int K,
                                                  const int* __restrict__ tinfo,
                                                  const int* __restrict__ order, int kblocks,
                                                  int OC, long long NPB, int NclampB,
                                                  const int* __restrict__ colmap) {
  __shared__ __align__(16) u16 As[128 * 64];
  __shared__ __align__(16) u16 Bs[128 * 64];
  int mt = blockIdx.x;
  int nt = order ? order[blockIdx.y] : blockIdx.y;
  int col0 = nt * 128, row0 = mt * 128;
  int tid = threadIdx.x, w = tid >> 6, l = tid & 63;
  int wm = w >> 1, wn = w & 1;
  int lr = l >> 3;
  int lk_sw = ((l & 7) ^ lr) * 8;
  f32x4 acc[4][4] = {};
  size_t aoff[4];
  size_t boff[4];
  #pragma unroll
  for (int r = 0; r < 4; ++r) {
    int chunk = r * 4 + w;
    int rowA = row0 + chunk * 8 + lr;
    aoff[r] = (size_t)rowA * K + lk_sw;
    int colB = col0 + chunk * 8 + lr;
    if (colB >= NclampB) colB = NclampB - 1;
    boff[r] = (size_t)colB * K + lk_sw;
  }
  int kbmin = 0, cnt = kblocks;
  if (tinfo) { kbmin = tinfo[2 * nt]; cnt = tinfo[2 * nt + 1]; }
  for (int i = 0; i < cnt; ++i) {
    int k0 = (kbmin + i) * 64;
    #pragma unroll
    for (int r = 0; r < 4; ++r) {
      int chunk = r * 4 + w;
      glds16(A + aoff[r] + k0, As + chunk * 512);
      glds16(B + boff[r] + k0, Bs + chunk * 512);
    }
    __syncthreads();
    mfma_stepT<4>(As, Bs, l, wm, wn, acc);
    __syncthreads();
  }
  epilogue_storeT<4>(acc, OUT, bias, row0, col0, l, wm, wn, N, OC, NPB, colmap);
}

// ---------- qprep as MFMA GEMM + fused start/end sigmoid heads ----------
// NOTE: e1buf/s1buf must NOT alias Qb (GEMM blocks run concurrently with sigmoid blocks)
__global__ __launch_bounds__(256, 2) void qprep_sig(const u16* __restrict__ Wq,
                                                    const u16* __restrict__ Pt,
                                                    u16* __restrict__ Qb,
                                                    const float* __restrict__ s1,
                                                    const float* __restrict__ e1,
                                                    const float* __restrict__ ws2,
                                                    const float* __restrict__ bs2,
                                                    const float* __restrict__ we2,
                                                    const float* __restrict__ be2,
                                                    float* __restrict__ out) {
  if (blockIdx.x == 128) {
    int t = threadIdx.x & 127;
    int sel = threadIdx.x >> 7;
    int bb = blockIdx.y;
    if (t >= 100) return;
    const float* in = sel ? e1 : s1;
    const float* w = sel ? we2 : ws2;
    float s = sel ? be2[0] : bs2[0];
    #pragma unroll 8
    for (int c = 0; c < 256; ++c) s += w[c] * in[((size_t)bb * 256 + c) * 100 + t];
    out[80000 + sel * 400 + bb * 100 + t] = sigmoidf_(s);
    return;
  }
  __shared__ __align__(16) u16 As[128 * 64];
  __shared__ __align__(16) u16 Bs[128 * 64];
  int mt = blockIdx.x, nt = blockIdx.y;
  int col0 = nt * 128, row0 = mt * 128;
  int tid = threadIdx.x, w = tid >> 6, l = tid & 63;
  int wm = w >> 1, wn = w & 1;
  int lr = l >> 3;
  int lk_sw = ((l & 7) ^ lr) * 8;
  f32x4 acc[4][4] = {};
  size_t aoff[4];
  size_t boff[4];
  #pragma unroll
  for (int r = 0; r < 4; ++r) {
    int chunk = r * 4 + w;
    int rowA = row0 + chunk * 8 + lr;
    aoff[r] = (size_t)rowA * 128 + lk_sw;
    int colB = col0 + chunk * 8 + lr;
    if (colB >= 400) colB = 399;
    boff[r] = (size_t)colB * 128 + lk_sw;
  }
  #pragma unroll
  for (int kb = 0; kb < 2; ++kb) {
    int k0 = kb * 64;
    #pragma unroll
    for (int r = 0; r < 4; ++r) {
      int chunk = r * 4 + w;
      glds16(Wq + aoff[r] + k0, As + chunk * 512);
      glds16(Pt + boff[r] + k0, Bs + chunk * 512);
    }
    __syncthreads();
    mfma_stepT<4>(As, Bs, l, wm, wn, acc);
    __syncthreads();
  }
  int r4 = (l >> 4) * 4, c1 = l & 15;
  #pragma unroll
  for (int i = 0; i < 4; ++i) {
    int row = row0 + wm * 64 + i * 16 + r4;
    int o = row >> 5, n = row & 31;
    #pragma unroll
    for (int j = 0; j < 4; ++j) {
      int col = col0 + wn * 64 + j * 16 + c1;
      if (col < 400) {
        int b = col / 100, t = col - b * 100;
        f32x4 v = acc[i][j];
        __align__(8) u16 h[4];
        h[0] = f2bf(v[0]);
        h[1] = f2bf(v[1]);
        h[2] = f2bf(v[2]);
        h[3] = f2bf(v[3]);
        *(uint2*)(Qb + ((size_t)(b * 512 + o)) * 3200 + t * 32 + n) = *(const uint2*)h;
      }
    }
  }
}

// ---------- 3x3 conv as shifted BT-GEMM; FUSE=1 computes conf head in-epilogue ----------
template<int FUSE>
__global__ __launch_bounds__(256, 2) void conv3x3_gemm(const u16* __restrict__ Apk,
                                                       const u16* __restrict__ X,
                                                       u16* __restrict__ OUT,
                                                       const float* __restrict__ bias,
                                                       const u16* __restrict__ zp,
                                                       const float* __restrict__ w2d,
                                                       const float* __restrict__ b2d,
                                                       float* __restrict__ out) {
  __shared__ __align__(16) u16 SH[2 * 128 * 64];   // As | Bs ; reused as head tile (32KB)
  u16* As = SH;
  u16* Bs = SH + 128 * 64;
  int nt = blockIdx.x;
  int col0 = nt * 128;
  int tid = threadIdx.x, w = tid >> 6, l = tid & 63;
  int wm = w >> 1, wn = w & 1;
  int lr = l >> 3;
  int lk_sw = ((l & 7) ^ lr) * 8;
  int cj[4], yy[4], xx[4];
  bool vv[4];
  size_t aoff[4];
  #pragma unroll
  for (int r = 0; r < 4; ++r) {
    int chunk = r * 4 + w;
    int c = col0 + chunk * 8 + lr;
    cj[r] = c;
    vv[r] = (c < 40000);
    int p = c % 10000;
    yy[r] = p / 100;
    xx[r] = p % 100;
    aoff[r] = (size_t)(chunk * 8 + lr) * 1152 + lk_sw;
  }
  f32x4 acc[4][4] = {};
  for (int s = 0; s < 9; ++s) {
    int dy = s / 3 - 1, dx = s % 3 - 1;
    int doff = dy * 100 + dx;
    #pragma unroll
    for (int half = 0; half < 2; ++half) {
      int k0 = s * 128 + half * 64;
      int c0 = half * 64;
      #pragma unroll
      for (int r = 0; r < 4; ++r) {
        int chunk = r * 4 + w;
        glds16(Apk + aoff[r] + k0, As + chunk * 512);
        int y2 = yy[r] + dy, x2 = xx[r] + dx;
        bool ok = vv[r] && ((unsigned)y2 < 100u) && ((unsigned)x2 < 100u);
        const u16* src = ok ? (X + (size_t)(cj[r] + doff) * 128 + c0 + lk_sw) : zp;
        glds16(src, Bs + chunk * 512);
      }
      __syncthreads();
      mfma_stepT<4>(As, Bs, l, wm, wn, acc);
      __syncthreads();
    }
  }
  if (FUSE == 0) {
    epilogue_storeT<4>(acc, OUT, bias, 0, col0, l, wm, wn, 40000, 128, 40000LL, nullptr);
  } else {
    // stage relu'd bf16 tile (128 ch x 128 cols) into LDS, swizzled u32 layout
    uint32_t* W = (uint32_t*)SH;
    int r4 = (l >> 4) * 4, c1 = l & 15;
    #pragma unroll
    for (int i = 0; i < 4; ++i) {
      int ob = wm * 64 + i * 16 + r4;
      float b0 = bias[ob + 0], b1 = bias[ob + 1], b2 = bias[ob + 2], b3 = bias[ob + 3];
      #pragma unroll
      for (int j = 0; j < 4; ++j) {
        int col = wn * 64 + j * 16 + c1;
        f32x4 v = acc[i][j];
        uint32_t lo = (uint32_t)f2bf(fmaxf(v[0] + b0, 0.f)) |
                      ((uint32_t)f2bf(fmaxf(v[1] + b1, 0.f)) << 16);
        uint32_t hi = (uint32_t)f2bf(fmaxf(v[2] + b2, 0.f)) |
                      ((uint32_t)f2bf(fmaxf(v[3] + b3, 0.f)) << 16);
        int jj = ob >> 1;
        W[col * 64 + (jj ^ (col & 31))] = lo;
        W[col * 64 + ((jj + 1) ^ (col & 31))] = hi;
      }
    }
    __syncthreads();
    int col = tid & 127, sel = tid >> 7;
    int gcol = col0 + col;
    if (gcol < 40000) {
      float sum = b2d[sel];
      const uint32_t* Wc = W + col * 64;
      const float* wd = w2d + sel * 128;
      #pragma unroll 8
      for (int c = 0; c < 64; ++c) {
        uint32_t v = Wc[c ^ (col & 31)];
        sum += wd[2 * c] * bf2f((u16)(v & 0xffffu)) + wd[2 * c + 1] * bf2f((u16)(v >> 16));
      }
      int b = gcol / 10000, pidx = gcol - b * 10000;
      out[((size_t)b * 2 + sel) * 10000 + pidx] = sigmoidf_(sum);
    }
  }
}

// ---------- launch ----------
extern "C" void kernel_launch(void* const* d_in, const int* in_sizes, int n_in, void* d_out,
                              int out_size, void* d_ws, size_t ws_size, hipStream_t stream) {
  const float* inputs = (const float*)d_in[0];
  const float* w_b1 = (const float*)d_in[1];
  const float* b_b1 = (const float*)d_in[2];
  const float* w_b2 = (const float*)d_in[3];
  const float* b_b2 = (const float*)d_in[4];
  const float* w_s1 = (const float*)d_in[5];
  const float* b_s1 = (const float*)d_in[6];
  const float* w_s2 = (const float*)d_in[7];
  const float* b_s2 = (const float*)d_in[8];
  const float* w_e1 = (const float*)d_in[9];
  const float* b_e1 = (const float*)d_in[10];
  const float* w_e2 = (const float*)d_in[11];
  const float* b_e2 = (const float*)d_in[12];
  const float* w_p1 = (const float*)d_in[13];
  const float* b_p1 = (const float*)d_in[14];
  const float* w3d = (const float*)d_in[15];
  const float* b3d = (const float*)d_in[16];
  const float* w2a = (const float*)d_in[17];
  const float* b2a = (const float*)d_in[18];
  const float* w2b = (const float*)d_in[19];
  const float* b2b = (const float*)d_in[20];
  const float* w2c = (const float*)d_in[21];
  const float* b2c = (const float*)d_in[22];
  const float* w2d = (const float*)d_in[23];
  const float* b2d = (const float*)d_in[24];
  float* out = (float*)d_out;
  char* ws = (char*)d_ws;

  int* tinfo = (int*)(ws + 0);
  int* order = (int*)(ws + 2048);
  u16* zp = (u16*)(ws + 16384);
  int* invperm = (int*)(ws + 45056);
  float* base1 = (float*)(ws + 90112);          // 409600
  float* base = (float*)(ws + 499712);          // 409600
  float* s1buf = (float*)(ws + 909312);         // 409600
  u16* Pt = (u16*)(ws + 1318912);               // 102400
  u16* w2a_bf = (u16*)(ws + 1421312);           // 131072
  u16* w2b_pk = (u16*)(ws + 1552384);           // 294912
  u16* w2c_pk = (u16*)(ws + 1847296);           // 294912
  u16* Qb = (u16*)(ws + 2142208);               // 13107200 (ends 15249408)
  u16* Mt = (u16*)(ws + 15249408);              // rows 0..5119 used -> ends 48017408
  float* e1buf = (float*)(ws + 48017408);       // 409600, in Mt-region free tail (no alias!)
  u16* C1t = (u16*)(ws + 79249408);             // 40960000  (end 120209408)
  u16* Wq = (u16*)(ws + 79249408);              // aliases C1t: dead before G1 writes C1t
  u16* x2t = Qb;   // alias: Qb dead after G1
  u16* x3t = C1t;  // alias: C1t dead after G2

  // 1) fused prep: weight casts, invperm, tile spans + order, zero page, mask rows, conv1
  prep_fused<<<2061, 256, 0, stream>>>(w2a, w2b, w2c, w2a_bf, w2b_pk, w2c_pk, w3d, Wq,
                                       invperm, tinfo, order, zp, Mt, inputs, w_b1, b_b1,
                                       base1);

  // 2-3) front end (fp32 exact, ILP-vectorized)
  conv1d_k3v<<<100, 256, 0, stream>>>(base1, w_b2, b_b2, base, 256, 64, 64, 256);
  conv1d_branch_v<<<250, 256, 0, stream>>>(base, w_s1, b_s1, w_e1, b_e1, w_p1, b_p1,
                                           s1buf, e1buf, Pt);

  // 4) qprep GEMM [16384 x 400 x 128] + fused start/end sigmoid heads
  qprep_sig<<<dim3(129, 4), 256, 0, stream>>>(Wq, Pt, Qb, s1buf, e1buf, w_s2, b_s2,
                                              w_e2, b_e2, out);

  // 5) G1: out3d, 128x128 tiles, longest-first; de-permuted store into C1t[(b,p)][o]
  gemm_bt<<<dim3(16, 79), 256, 0, stream>>>(Qb, Mt, C1t, b3d, 10000, 3200, tinfo, order, 50,
                                            512, 10000LL, 10000, invperm);
  // 6) G2: 1x1 conv 512->128
  gemm_bt<<<dim3(1, 313), 256, 0, stream>>>(w2a_bf, C1t, x2t, b2a, 40000, 512, nullptr,
                                            nullptr, 8, 128, 40000LL, 40000, nullptr);
  // 7) G3: 3x3 conv 128->128
  conv3x3_gemm<0><<<dim3(313), 256, 0, stream>>>(w2b_pk, x2t, x3t, b2b, zp, nullptr, nullptr,
                                                 nullptr);
  // 8) G4: 3x3 conv 128->128 + fused conf head (no x4 global round-trip)
  conv3x3_gemm<1><<<dim3(313), 256, 0, stream>>>(w2c_pk, x3t, nullptr, b2c, zp, w2d, b2d,
                                                 out);
}